// Round 3
// baseline (250.670 us; speedup 1.0000x reference)
//
#include <hip/hip_runtime.h>
#include <math.h>

#define B_  8
#define H_  8
#define C_  512
#define L_  1024
#define DH  64
#define WIN 4

typedef __attribute__((ext_vector_type(8))) short short8;
typedef __attribute__((ext_vector_type(4))) float floatx4;

__device__ __forceinline__ unsigned short f2bf(float f) {
    unsigned int u = __float_as_uint(f);
    u = u + 0x7FFFu + ((u >> 16) & 1u);     // RNE
    return (unsigned short)(u >> 16);
}
__device__ __forceinline__ float bf2f(unsigned short h) {
    return __uint_as_float(((unsigned int)h) << 16);
}
__device__ __forceinline__ unsigned short f2h(float f) {
    _Float16 h = (_Float16)f;
    return *reinterpret_cast<unsigned short*>(&h);
}

// ---------------------------------------------------------------------------
// prep: Wq/Wk/Wv -> bf16 (packed 3x512x512), Wo -> f16, pack biases.
// ---------------------------------------------------------------------------
__global__ __launch_bounds__(256) void prep_kernel(
    const float* __restrict__ Wq, const float* __restrict__ Wk,
    const float* __restrict__ Wv, const float* __restrict__ Wo,
    const float* __restrict__ bq, const float* __restrict__ bk,
    const float* __restrict__ bv,
    unsigned short* __restrict__ Wqkv_hi,
    unsigned short* __restrict__ Wo_h,
    float* __restrict__ bqkv)
{
    const int i = blockIdx.x * 256 + threadIdx.x;   // 65536 float4 slots
    float4 v; ushort4 h;

    v = ((const float4*)Wq)[i];
    h.x = f2bf(v.x); h.y = f2bf(v.y); h.z = f2bf(v.z); h.w = f2bf(v.w);
    ((ushort4*)Wqkv_hi)[i] = h;

    v = ((const float4*)Wk)[i];
    h.x = f2bf(v.x); h.y = f2bf(v.y); h.z = f2bf(v.z); h.w = f2bf(v.w);
    ((ushort4*)Wqkv_hi)[65536 + i] = h;

    v = ((const float4*)Wv)[i];
    h.x = f2bf(v.x); h.y = f2bf(v.y); h.z = f2bf(v.z); h.w = f2bf(v.w);
    ((ushort4*)Wqkv_hi)[131072 + i] = h;

    v = ((const float4*)Wo)[i];
    h.x = f2h(v.x); h.y = f2h(v.y); h.z = f2h(v.z); h.w = f2h(v.w);
    ((ushort4*)Wo_h)[i] = h;

    if (i < 512)       bqkv[i] = bq[i];
    else if (i < 1024) bqkv[i] = bk[i - 512];
    else if (i < 1536) bqkv[i] = bv[i - 1024];
}

// ---------------------------------------------------------------------------
// x (B,C,L) fp32 -> xT bf16 (B,L,C).  32x32 LDS transpose.
// ---------------------------------------------------------------------------
__global__ __launch_bounds__(256) void transpose_kernel(
    const float* __restrict__ x, unsigned short* __restrict__ xT)
{
    __shared__ float tile[32][33];
    const int b  = blockIdx.z;
    const int cb = blockIdx.y * 32;
    const int lb = blockIdx.x * 32;
    const int t  = threadIdx.x;
    {
        const int l = t & 31, c0 = t >> 5;
#pragma unroll
        for (int p = 0; p < 4; ++p) {
            const int c = c0 + 8 * p;
            tile[c][l] = x[((size_t)b * C_ + cb + c) * L_ + lb + l];
        }
    }
    __syncthreads();
    {
        const int c = t & 31, l0 = t >> 5;
#pragma unroll
        for (int p = 0; p < 4; ++p) {
            const int l = l0 + 8 * p;
            xT[((size_t)b * L_ + lb + l) * C_ + cb + c] = f2bf(tile[c][l]);
        }
    }
}

// ---------------------------------------------------------------------------
// Fused QKV GEMM v2: double-buffered LDS + register prefetch, ONE barrier
// per K-step.  Epilogue: single-pass dual-head LDS transpose for Q/K,
// direct coalesced (B,C,L) for V.
// ---------------------------------------------------------------------------
__global__ __launch_bounds__(256) void qkv_gemm_kernel(
    const unsigned short* __restrict__ Wh, const float* __restrict__ bqkv,
    const unsigned short* __restrict__ xT,
    unsigned short* __restrict__ Qb, unsigned short* __restrict__ Kb,
    unsigned short* __restrict__ Vc)
{
    // [A=0/B=1][buf][row][40] = 40 KB; epilogue sT[128][144] (36.9 KB) aliases it
    __shared__ __align__(16) unsigned short AB[2][2][128][40];

    const int b   = blockIdx.z;
    const int oB  = blockIdx.y * 128;
    const int mat = oB >> 9;                // 0=Q,1=K,2=V
    const int ob  = oB & 511;
    const int lb  = blockIdx.x * 128;
    const int t  = threadIdx.x;
    const int w = t >> 6, lane = t & 63, quad = lane >> 4, lc = lane & 15;
    const int wm = w >> 1, wn = w & 1;

    const unsigned short* Wm = Wh + (size_t)mat * C_ * C_;

    floatx4 acc[4][4];
#pragma unroll
    for (int i = 0; i < 4; ++i)
#pragma unroll
        for (int j = 0; j < 4; ++j) acc[i][j] = (floatx4)0.f;

    const int c8 = (t & 3) * 8, r0 = t >> 2;

    // stage K-step 0 into buffer 0
#pragma unroll
    for (int p = 0; p < 2; ++p) {
        *reinterpret_cast<uint4*>(&AB[0][0][r0 + 64 * p][c8]) =
            *reinterpret_cast<const uint4*>(&Wm[(size_t)(ob + r0 + 64 * p) * C_ + c8]);
        *reinterpret_cast<uint4*>(&AB[1][0][r0 + 64 * p][c8]) =
            *reinterpret_cast<const uint4*>(&xT[((size_t)b * L_ + lb + r0 + 64 * p) * C_ + c8]);
    }
    __syncthreads();

    for (int s = 0; s < 16; ++s) {
        const int cur = s & 1;

        // register prefetch of step s+1 (hidden under the MFMAs below)
        uint4 pa[2], pb[2];
        if (s < 15) {
            const int c0n = (s + 1) * 32;
#pragma unroll
            for (int p = 0; p < 2; ++p) {
                pa[p] = *reinterpret_cast<const uint4*>(
                    &Wm[(size_t)(ob + r0 + 64 * p) * C_ + c0n + c8]);
                pb[p] = *reinterpret_cast<const uint4*>(
                    &xT[((size_t)b * L_ + lb + r0 + 64 * p) * C_ + c0n + c8]);
            }
        }

        short8 a[4], bb[4];
#pragma unroll
        for (int mt = 0; mt < 4; ++mt)
            a[mt] = *reinterpret_cast<const short8*>(
                &AB[0][cur][wm * 64 + mt * 16 + lc][quad * 8]);
#pragma unroll
        for (int nt = 0; nt < 4; ++nt)
            bb[nt] = *reinterpret_cast<const short8*>(
                &AB[1][cur][wn * 64 + nt * 16 + lc][quad * 8]);
#pragma unroll
        for (int mt = 0; mt < 4; ++mt)
#pragma unroll
            for (int nt = 0; nt < 4; ++nt)
                acc[mt][nt] = __builtin_amdgcn_mfma_f32_16x16x32_bf16(
                    a[mt], bb[nt], acc[mt][nt], 0, 0, 0);

        if (s < 15) {
#pragma unroll
            for (int p = 0; p < 2; ++p) {
                *reinterpret_cast<uint4*>(&AB[0][1 - cur][r0 + 64 * p][c8]) = pa[p];
                *reinterpret_cast<uint4*>(&AB[1][1 - cur][r0 + 64 * p][c8]) = pb[p];
            }
        }
        __syncthreads();
    }

    if (mat == 2) {
        // V: direct coalesced (B,C,L)
#pragma unroll
        for (int mt = 0; mt < 4; ++mt) {
#pragma unroll
            for (int r = 0; r < 4; ++r) {
                const int o  = ob + wm * 64 + mt * 16 + quad * 4 + r;
                const float bi = bqkv[1024 + o];
#pragma unroll
                for (int nt = 0; nt < 4; ++nt) {
                    const int l = lb + wn * 64 + nt * 16 + lc;
                    Vc[((size_t)b * C_ + o) * L_ + l] = f2bf(acc[mt][nt][r] + bi);
                }
            }
        }
    } else {
        // Q/K: single-pass dual-head LDS transpose (sT aliases AB; the final
        // K-loop barrier has retired all reads of AB)
        const float scale = (mat == 0) ? 0.125f : 1.0f;
        unsigned short* dst = (mat == 0) ? Qb : Kb;
        unsigned short (*sT)[144] =
            reinterpret_cast<unsigned short (*)[144]>(&AB[0][0][0][0]);

        // wave (wm, wn): head wm, l-range wn*64..+63 — all waves concurrent
#pragma unroll
        for (int mt = 0; mt < 4; ++mt) {
#pragma unroll
            for (int r = 0; r < 4; ++r) {
                const int o  = ob + wm * 64 + mt * 16 + quad * 4 + r;
                const float bi = bqkv[mat * 512 + o];
                const int d  = mt * 16 + quad * 4 + r;
#pragma unroll
                for (int nt = 0; nt < 4; ++nt) {
                    const int l = wn * 64 + nt * 16 + lc;
                    sT[l][wm * 72 + d] = f2bf((acc[mt][nt][r] + bi) * scale);
                }
            }
        }
        __syncthreads();
        {
            const int l = t >> 1, hf = t & 1;
#pragma unroll
            for (int h01 = 0; h01 < 2; ++h01) {
                const int hgl = (ob >> 6) + h01;
                const size_t o = (((size_t)b * H_ + hgl) * L_ + lb + l) * DH + hf * 32;
                const int cbase = h01 * 72 + hf * 32;
                uint4 v0 = *reinterpret_cast<const uint4*>(&sT[l][cbase]);
                uint4 v1 = *reinterpret_cast<const uint4*>(&sT[l][cbase + 8]);
                uint4 v2 = *reinterpret_cast<const uint4*>(&sT[l][cbase + 16]);
                uint4 v3 = *reinterpret_cast<const uint4*>(&sT[l][cbase + 24]);
                *reinterpret_cast<uint4*>(&dst[o])      = v0;
                *reinterpret_cast<uint4*>(&dst[o + 8])  = v1;
                *reinterpret_cast<uint4*>(&dst[o + 16]) = v2;
                *reinterpret_cast<uint4*>(&dst[o + 24]) = v3;
            }
        }
    }
}

// ---------------------------------------------------------------------------
// Attention v11: BARRIER-FREE.  v9/v10 proved the compiler re-serializes any
// wave-internal MFMA/VALU interleave; the real structural cost is the
// per-tile __syncthreads lockstep that phase-aligns all 8 waves (all QK
// together, all exp together -> each pipe idles in turn at 4 waves/SIMD).
// K/V LDS staging is unnecessary: per (b,h) K+V = 256 KB; the bh%8 XCD
// mapping gives each XCD an 8-batch working set of 2 MB < 4 MB L2, and both
// K and V fragments are 16B-contiguous direct global reads (L1 filters the
// 8x intra-block re-read).  So: no kst/vst, no staging, no prefetch, ZERO
// barriers (Pl/rs/rv are wave-private; same-wave DS is in-order).  Waves
// free-run and self-stagger into complementary pipe phases; global loads
// for tile t+1 hoist across exp(t) under counted vmcnt with no barrier in
// the way.  LDS 61.4 -> 26.6 KB.  Numerics identical to v8.
// ---------------------------------------------------------------------------
__global__ __launch_bounds__(512, 4) void attn_kernel11(
    const unsigned short* __restrict__ Qb,   // bf16 (B,H,L,Dh), pre-scaled
    const unsigned short* __restrict__ Kb,   // bf16 (B,H,L,Dh)
    const unsigned short* __restrict__ Vc,   // bf16 (B,C,L)
    const float* __restrict__ erel_k, const float* __restrict__ erel_v,
    unsigned short* __restrict__ AOh)        // f16 (B,L,C)
{
    __shared__ __align__(16) unsigned short Pl[8][16][68];   // per-wave P
    __shared__ float rs[128][9];
    __shared__ float rv[128][9];

    const int t  = threadIdx.x;
    const int bh = blockIdx.x;          // 0..63  (id%8==h -> XCD L2 locality)
    const int rt = blockIdx.y;          // 0..7
    const int b = bh >> 3, h = bh & 7;
    const int w = t >> 6, lane = t & 63, quad = lane >> 4, lc = lane & 15;
    const int row0 = rt * 128;
    const int rowW = row0 + w * 16;     // wave's 16 rows

    const size_t qkBase = (size_t)bh * L_ * DH;
    const size_t vBase  = ((size_t)b * C_ + h * DH) * L_;

    for (int i = lane; i < 16 * 9; i += 64) rv[w * 16 + i / 9][i % 9] = 0.f;

    // Q A-fragments (16 rows), reused across all 16 key tiles
    short8 af[2];
#pragma unroll
    for (int kk = 0; kk < 2; ++kk)
        af[kk] = *reinterpret_cast<const short8*>(
            &Qb[qkBase + (size_t)(rowW + lc) * DH + kk * 32 + quad * 8]);

    // rel-k scores via MFMA: B[n=dr][k=d] = erk[dr][d]  (wave-private rows)
    {
        floatx4 rsa = (floatx4)0.f;
        const int drow = (lc < 9) ? lc : 8;
#pragma unroll
        for (int kk = 0; kk < 2; ++kk) {
            short8 bfr;
#pragma unroll
            for (int i = 0; i < 8; ++i)
                bfr[i] = (short)f2bf(erel_k[drow * 64 + kk * 32 + quad * 8 + i]);
            rsa = __builtin_amdgcn_mfma_f32_16x16x32_bf16(af[kk], bfr, rsa, 0, 0, 0);
        }
        if (lc < 9) {
#pragma unroll
            for (int r = 0; r < 4; ++r)
                rs[w * 16 + quad * 4 + r][lc] = rsa[r];
        }
    }

    short8 ones;
#pragma unroll
    for (int j = 0; j < 8; ++j) ones[j] = (short)0x3F80;

    floatx4 acc_o[4], acc_l = (floatx4)0.f;
#pragma unroll
    for (int nt = 0; nt < 4; ++nt) acc_o[nt] = (floatx4)0.f;

    // ---- main loop: 16 key tiles, NO barriers, direct-global K/V ---------
    for (int jt = 0; jt < L_ / 64; ++jt) {
        const int j0 = jt * 64;

        // S = Q K^T   (K B-fragments straight from global; 16B contiguous)
        floatx4 sacc[4];
#pragma unroll
        for (int nt = 0; nt < 4; ++nt) sacc[nt] = (floatx4)0.f;
#pragma unroll
        for (int nt = 0; nt < 4; ++nt)
#pragma unroll
            for (int kk = 0; kk < 2; ++kk) {
                const short8 kf = *reinterpret_cast<const short8*>(
                    &Kb[qkBase + (size_t)(j0 + nt * 16 + lc) * DH + kk * 32 + quad * 8]);
                sacc[nt] = __builtin_amdgcn_mfma_f32_16x16x32_bf16(
                    af[kk], kf, sacc[nt], 0, 0, 0);
            }

        // windowed rel-k bias (near-diagonal tiles only)
        const bool nearD = (j0 <= rowW + 15 + WIN) && (j0 + 63 >= rowW - WIN);
        if (nearD) {
#pragma unroll
            for (int nt = 0; nt < 4; ++nt) {
                const int jg = j0 + nt * 16 + lc;
#pragma unroll
                for (int r = 0; r < 4; ++r) {
                    const int diff = jg - (rowW + quad * 4 + r);
                    if (diff >= -WIN && diff <= WIN)
                        sacc[nt][r] += rs[w * 16 + quad * 4 + r][diff + WIN];
                }
            }
        }

        // exp (no max subtraction; scores bounded ~|6|), P -> LDS bf16
#pragma unroll
        for (int nt = 0; nt < 4; ++nt)
#pragma unroll
            for (int r = 0; r < 4; ++r)
                Pl[w][quad * 4 + r][nt * 16 + lc] = f2bf(__expf(sacc[nt][r]));

        // rel-v prob accumulation (gated; wave-private rows, in-order DS)
        if (nearD) {
            for (int idx = lane; idx < 16 * 9; idx += 64) {
                const int r16 = idx / 9, dr = idx % 9;
                const int jg = rowW + r16 + dr - WIN;
                if (jg >= j0 && jg < j0 + 64 && jg >= 0 && jg < L_)
                    rv[w * 16 + r16][dr] += bf2f(Pl[w][r16][jg - j0]);
            }
        }

        // P back as A-fragments
        short8 pf[2];
#pragma unroll
        for (int kk = 0; kk < 2; ++kk)
            pf[kk] = *reinterpret_cast<const short8*>(&Pl[w][lc][kk * 32 + quad * 8]);

        // row sums via MFMA
#pragma unroll
        for (int kk = 0; kk < 2; ++kk)
            acc_l = __builtin_amdgcn_mfma_f32_16x16x32_bf16(pf[kk], ones, acc_l, 0, 0, 0);

        // O += P V   (V B-fragments straight from global; 16B contiguous)
#pragma unroll
        for (int nt = 0; nt < 4; ++nt)
#pragma unroll
            for (int kk = 0; kk < 2; ++kk) {
                const short8 vf = *reinterpret_cast<const short8*>(
                    &Vc[vBase + (size_t)(nt * 16 + lc) * L_ + j0 + kk * 32 + quad * 8]);
                acc_o[nt] = __builtin_amdgcn_mfma_f32_16x16x32_bf16(
                    pf[kk], vf, acc_o[nt], 0, 0, 0);
            }
    }

    // epilogue: rel-v term, normalize, transpose via Pl, full-line f16 stores
#pragma unroll
    for (int nt = 0; nt < 4; ++nt) {
        const int d = nt * 16 + lc;
        float ev[9];
#pragma unroll
        for (int dr = 0; dr < 9; ++dr) ev[dr] = erel_v[dr * 64 + d];
#pragma unroll
        for (int r = 0; r < 4; ++r) {
            const int rloc = w * 16 + quad * 4 + r;
            float v = acc_o[nt][r];
#pragma unroll
            for (int dr = 0; dr < 9; ++dr) v += rv[rloc][dr] * ev[dr];
            Pl[w][quad * 4 + r][nt * 16 + lc] = f2h(v / acc_l[r]);
        }
    }
    {
        const int row = lane >> 2, ds8 = (lane & 3) * 16;
        const uint4 q0 = *reinterpret_cast<const uint4*>(&Pl[w][row][ds8]);
        const uint4 q1 = *reinterpret_cast<const uint4*>(&Pl[w][row][ds8 + 8]);
        const size_t o = ((size_t)b * L_ + rowW + row) * C_ + h * 64 + ds8;
        *reinterpret_cast<uint4*>(&AOh[o])     = q0;
        *reinterpret_cast<uint4*>(&AOh[o + 8]) = q1;
    }
}

// ---------------------------------------------------------------------------
// Output projection v2: 1-term f16, double-buffered LDS + register prefetch,
// one barrier per K-step.  M-tile 128 x N-tile 64 x K=512.
// ---------------------------------------------------------------------------
__global__ __launch_bounds__(256) void out_gemm_kernel(
    const unsigned short* __restrict__ Wh,
    const float* __restrict__ bo,
    const unsigned short* __restrict__ Ah,
    float* __restrict__ Y)
{
    __shared__ __align__(16) unsigned short Asb[2][128][40];
    __shared__ __align__(16) unsigned short Bsb[2][64][40];

    const int b  = blockIdx.z;
    const int ob = blockIdx.y * 128;
    const int lb = blockIdx.x * 64;
    const int t  = threadIdx.x;
    const int w = t >> 6, lane = t & 63, quad = lane >> 4, lc = lane & 15;
    const int wm = w >> 1, wn = w & 1;

    floatx4 acc[4][2];
#pragma unroll
    for (int i = 0; i < 4; ++i)
#pragma unroll
        for (int j = 0; j < 2; ++j) acc[i][j] = (floatx4)0.f;

    const int c8 = (t & 3) * 8, r0 = t >> 2;

    // stage step 0
#pragma unroll
    for (int p = 0; p < 2; ++p)
        *reinterpret_cast<uint4*>(&Asb[0][r0 + 64 * p][c8]) =
            *reinterpret_cast<const uint4*>(&Wh[(size_t)(ob + r0 + 64 * p) * C_ + c8]);
    *reinterpret_cast<uint4*>(&Bsb[0][r0][c8]) =
        *reinterpret_cast<const uint4*>(&Ah[((size_t)b * L_ + lb + r0) * C_ + c8]);
    __syncthreads();

    for (int s = 0; s < 16; ++s) {
        const int cur = s & 1;

        uint4 pa[2], pb;
        if (s < 15) {
            const int c0n = (s + 1) * 32;
#pragma unroll
            for (int p = 0; p < 2; ++p)
                pa[p] = *reinterpret_cast<const uint4*>(
                    &Wh[(size_t)(ob + r0 + 64 * p) * C_ + c0n + c8]);
            pb = *reinterpret_cast<const uint4*>(
                &Ah[((size_t)b * L_ + lb + r0) * C_ + c0n + c8]);
        }

        short8 ah[4], bhf[2];
#pragma unroll
        for (int mt = 0; mt < 4; ++mt)
            ah[mt] = *reinterpret_cast<const short8*>(
                &Asb[cur][wm * 64 + mt * 16 + lc][quad * 8]);
#pragma unroll
        for (int nt = 0; nt < 2; ++nt)
            bhf[nt] = *reinterpret_cast<const short8*>(
                &Bsb[cur][wn * 32 + nt * 16 + lc][quad * 8]);
#pragma unroll
        for (int mt = 0; mt < 4; ++mt)
#pragma unroll
            for (int nt = 0; nt < 2; ++nt)
                acc[mt][nt] = __builtin_amdgcn_mfma_f32_16x16x32_f16(
                    ah[mt], bhf[nt], acc[mt][nt], 0, 0, 0);

        if (s < 15) {
#pragma unroll
            for (int p = 0; p < 2; ++p)
                *reinterpret_cast<uint4*>(&Asb[1 - cur][r0 + 64 * p][c8]) = pa[p];
            *reinterpret_cast<uint4*>(&Bsb[1 - cur][r0][c8]) = pb;
        }
        __syncthreads();
    }

#pragma unroll
    for (int mt = 0; mt < 4; ++mt) {
#pragma unroll
        for (int r = 0; r < 4; ++r) {
            const int o = ob + wm * 64 + mt * 16 + quad * 4 + r;
            const float bi = bo[o];
#pragma unroll
            for (int nt = 0; nt < 2; ++nt) {
                const int l = lb + wn * 32 + nt * 16 + lc;
                Y[((size_t)b * C_ + o) * L_ + l] = acc[mt][nt][r] + bi;
            }
        }
    }
}

// ---------------------------------------------------------------------------
extern "C" void kernel_launch(void* const* d_in, const int* in_sizes, int n_in,
                              void* d_out, int out_size, void* d_ws, size_t ws_size,
                              hipStream_t stream)
{
    const float* x   = (const float*)d_in[0];
    const float* Wq  = (const float*)d_in[1];
    const float* bq  = (const float*)d_in[2];
    const float* Wk  = (const float*)d_in[3];
    const float* bk  = (const float*)d_in[4];
    const float* Wv  = (const float*)d_in[5];
    const float* bv  = (const float*)d_in[6];
    const float* Wo  = (const float*)d_in[7];
    const float* bo  = (const float*)d_in[8];
    const float* erk = (const float*)d_in[9];
    const float* erv = (const float*)d_in[10];

    char* ws = (char*)d_ws;
    const size_t MB = 1024u * 1024u;
    unsigned short* xT      = (unsigned short*)(ws);             // 8 MB
    unsigned short* Qb      = (unsigned short*)(ws + 8 * MB);    // 8 MB (B,H,L,Dh)
    unsigned short* Kb      = (unsigned short*)(ws + 16 * MB);   // 8 MB (B,H,L,Dh)
    unsigned short* Vc      = (unsigned short*)(ws + 24 * MB);   // 8 MB (B,C,L)
    unsigned short* AOh     = (unsigned short*)(ws + 32 * MB);   // 8 MB f16 (B,L,C)
    unsigned short* Wqkv_hi = (unsigned short*)(ws + 40 * MB);   // 1.5 MB
    unsigned short* Wo_h    = (unsigned short*)(ws + 42 * MB);   // 0.5 MB f16
    float*          bqkv    = (float*)(ws + 43 * MB);            // 6 KB

    prep_kernel<<<256, 256, 0, stream>>>(Wq, Wk, Wv, Wo, bq, bk, bv,
                                         Wqkv_hi, Wo_h, bqkv);
    transpose_kernel<<<dim3(L_ / 32, C_ / 32, B_), 256, 0, stream>>>(x, xT);
    qkv_gemm_kernel<<<dim3(L_ / 128, 12, B_), 256, 0, stream>>>(
        Wqkv_hi, bqkv, xT, Qb, Kb, Vc);
    attn_kernel11<<<dim3(64, 8), 512, 0, stream>>>(
        Qb, Kb, Vc, erk, erv, AOh);
    out_gemm_kernel<<<dim3(L_ / 64, C_ / 128, B_), 256, 0, stream>>>(
        Wo_h, bo, AOh, (float*)d_out);
}

// Round 4
// 169.742 us; speedup vs baseline: 1.4768x; 1.4768x over previous
//
#include <hip/hip_runtime.h>
#include <math.h>

#define B_  8
#define H_  8
#define C_  512
#define L_  1024
#define DH  64
#define WIN 4

typedef __attribute__((ext_vector_type(8))) short short8;
typedef __attribute__((ext_vector_type(4))) float floatx4;

__device__ __forceinline__ unsigned short f2bf(float f) {
    unsigned int u = __float_as_uint(f);
    u = u + 0x7FFFu + ((u >> 16) & 1u);     // RNE
    return (unsigned short)(u >> 16);
}
__device__ __forceinline__ float bf2f(unsigned short h) {
    return __uint_as_float(((unsigned int)h) << 16);
}
__device__ __forceinline__ unsigned short f2h(float f) {
    _Float16 h = (_Float16)f;
    return *reinterpret_cast<unsigned short*>(&h);
}

// ---------------------------------------------------------------------------
// prep: Wq/Wk/Wv -> bf16 (packed 3x512x512), Wo -> f16, pack biases.
// ---------------------------------------------------------------------------
__global__ __launch_bounds__(256) void prep_kernel(
    const float* __restrict__ Wq, const float* __restrict__ Wk,
    const float* __restrict__ Wv, const float* __restrict__ Wo,
    const float* __restrict__ bq, const float* __restrict__ bk,
    const float* __restrict__ bv,
    unsigned short* __restrict__ Wqkv_hi,
    unsigned short* __restrict__ Wo_h,
    float* __restrict__ bqkv)
{
    const int i = blockIdx.x * 256 + threadIdx.x;   // 65536 float4 slots
    float4 v; ushort4 h;

    v = ((const float4*)Wq)[i];
    h.x = f2bf(v.x); h.y = f2bf(v.y); h.z = f2bf(v.z); h.w = f2bf(v.w);
    ((ushort4*)Wqkv_hi)[i] = h;

    v = ((const float4*)Wk)[i];
    h.x = f2bf(v.x); h.y = f2bf(v.y); h.z = f2bf(v.z); h.w = f2bf(v.w);
    ((ushort4*)Wqkv_hi)[65536 + i] = h;

    v = ((const float4*)Wv)[i];
    h.x = f2bf(v.x); h.y = f2bf(v.y); h.z = f2bf(v.z); h.w = f2bf(v.w);
    ((ushort4*)Wqkv_hi)[131072 + i] = h;

    v = ((const float4*)Wo)[i];
    h.x = f2h(v.x); h.y = f2h(v.y); h.z = f2h(v.z); h.w = f2h(v.w);
    ((ushort4*)Wo_h)[i] = h;

    if (i < 512)       bqkv[i] = bq[i];
    else if (i < 1024) bqkv[i] = bk[i - 512];
    else if (i < 1536) bqkv[i] = bv[i - 1024];
}

// ---------------------------------------------------------------------------
// x (B,C,L) fp32 -> xT bf16 (B,L,C).  32x32 LDS transpose.
// ---------------------------------------------------------------------------
__global__ __launch_bounds__(256) void transpose_kernel(
    const float* __restrict__ x, unsigned short* __restrict__ xT)
{
    __shared__ float tile[32][33];
    const int b  = blockIdx.z;
    const int cb = blockIdx.y * 32;
    const int lb = blockIdx.x * 32;
    const int t  = threadIdx.x;
    {
        const int l = t & 31, c0 = t >> 5;
#pragma unroll
        for (int p = 0; p < 4; ++p) {
            const int c = c0 + 8 * p;
            tile[c][l] = x[((size_t)b * C_ + cb + c) * L_ + lb + l];
        }
    }
    __syncthreads();
    {
        const int c = t & 31, l0 = t >> 5;
#pragma unroll
        for (int p = 0; p < 4; ++p) {
            const int l = l0 + 8 * p;
            xT[((size_t)b * L_ + lb + l) * C_ + cb + c] = f2bf(tile[c][l]);
        }
    }
}

// ---------------------------------------------------------------------------
// Fused QKV GEMM v2: double-buffered LDS + register prefetch, ONE barrier
// per K-step.  Epilogue: single-pass dual-head LDS transpose for Q/K,
// direct coalesced (B,C,L) for V.
// ---------------------------------------------------------------------------
__global__ __launch_bounds__(256) void qkv_gemm_kernel(
    const unsigned short* __restrict__ Wh, const float* __restrict__ bqkv,
    const unsigned short* __restrict__ xT,
    unsigned short* __restrict__ Qb, unsigned short* __restrict__ Kb,
    unsigned short* __restrict__ Vc)
{
    // [A=0/B=1][buf][row][40] = 40 KB; epilogue sT[128][144] (36.9 KB) aliases it
    __shared__ __align__(16) unsigned short AB[2][2][128][40];

    const int b   = blockIdx.z;
    const int oB  = blockIdx.y * 128;
    const int mat = oB >> 9;                // 0=Q,1=K,2=V
    const int ob  = oB & 511;
    const int lb  = blockIdx.x * 128;
    const int t  = threadIdx.x;
    const int w = t >> 6, lane = t & 63, quad = lane >> 4, lc = lane & 15;
    const int wm = w >> 1, wn = w & 1;

    const unsigned short* Wm = Wh + (size_t)mat * C_ * C_;

    floatx4 acc[4][4];
#pragma unroll
    for (int i = 0; i < 4; ++i)
#pragma unroll
        for (int j = 0; j < 4; ++j) acc[i][j] = (floatx4)0.f;

    const int c8 = (t & 3) * 8, r0 = t >> 2;

    // stage K-step 0 into buffer 0
#pragma unroll
    for (int p = 0; p < 2; ++p) {
        *reinterpret_cast<uint4*>(&AB[0][0][r0 + 64 * p][c8]) =
            *reinterpret_cast<const uint4*>(&Wm[(size_t)(ob + r0 + 64 * p) * C_ + c8]);
        *reinterpret_cast<uint4*>(&AB[1][0][r0 + 64 * p][c8]) =
            *reinterpret_cast<const uint4*>(&xT[((size_t)b * L_ + lb + r0 + 64 * p) * C_ + c8]);
    }
    __syncthreads();

    for (int s = 0; s < 16; ++s) {
        const int cur = s & 1;

        // register prefetch of step s+1 (hidden under the MFMAs below)
        uint4 pa[2], pb[2];
        if (s < 15) {
            const int c0n = (s + 1) * 32;
#pragma unroll
            for (int p = 0; p < 2; ++p) {
                pa[p] = *reinterpret_cast<const uint4*>(
                    &Wm[(size_t)(ob + r0 + 64 * p) * C_ + c0n + c8]);
                pb[p] = *reinterpret_cast<const uint4*>(
                    &xT[((size_t)b * L_ + lb + r0 + 64 * p) * C_ + c0n + c8]);
            }
        }

        short8 a[4], bb[4];
#pragma unroll
        for (int mt = 0; mt < 4; ++mt)
            a[mt] = *reinterpret_cast<const short8*>(
                &AB[0][cur][wm * 64 + mt * 16 + lc][quad * 8]);
#pragma unroll
        for (int nt = 0; nt < 4; ++nt)
            bb[nt] = *reinterpret_cast<const short8*>(
                &AB[1][cur][wn * 64 + nt * 16 + lc][quad * 8]);
#pragma unroll
        for (int mt = 0; mt < 4; ++mt)
#pragma unroll
            for (int nt = 0; nt < 4; ++nt)
                acc[mt][nt] = __builtin_amdgcn_mfma_f32_16x16x32_bf16(
                    a[mt], bb[nt], acc[mt][nt], 0, 0, 0);

        if (s < 15) {
#pragma unroll
            for (int p = 0; p < 2; ++p) {
                *reinterpret_cast<uint4*>(&AB[0][1 - cur][r0 + 64 * p][c8]) = pa[p];
                *reinterpret_cast<uint4*>(&AB[1][1 - cur][r0 + 64 * p][c8]) = pb[p];
            }
        }
        __syncthreads();
    }

    if (mat == 2) {
        // V: direct coalesced (B,C,L)
#pragma unroll
        for (int mt = 0; mt < 4; ++mt) {
#pragma unroll
            for (int r = 0; r < 4; ++r) {
                const int o  = ob + wm * 64 + mt * 16 + quad * 4 + r;
                const float bi = bqkv[1024 + o];
#pragma unroll
                for (int nt = 0; nt < 4; ++nt) {
                    const int l = lb + wn * 64 + nt * 16 + lc;
                    Vc[((size_t)b * C_ + o) * L_ + l] = f2bf(acc[mt][nt][r] + bi);
                }
            }
        }
    } else {
        // Q/K: single-pass dual-head LDS transpose (sT aliases AB; the final
        // K-loop barrier has retired all reads of AB)
        const float scale = (mat == 0) ? 0.125f : 1.0f;
        unsigned short* dst = (mat == 0) ? Qb : Kb;
        unsigned short (*sT)[144] =
            reinterpret_cast<unsigned short (*)[144]>(&AB[0][0][0][0]);

        // wave (wm, wn): head wm, l-range wn*64..+63 — all waves concurrent
#pragma unroll
        for (int mt = 0; mt < 4; ++mt) {
#pragma unroll
            for (int r = 0; r < 4; ++r) {
                const int o  = ob + wm * 64 + mt * 16 + quad * 4 + r;
                const float bi = bqkv[mat * 512 + o];
                const int d  = mt * 16 + quad * 4 + r;
#pragma unroll
                for (int nt = 0; nt < 4; ++nt) {
                    const int l = wn * 64 + nt * 16 + lc;
                    sT[l][wm * 72 + d] = f2bf((acc[mt][nt][r] + bi) * scale);
                }
            }
        }
        __syncthreads();
        {
            const int l = t >> 1, hf = t & 1;
#pragma unroll
            for (int h01 = 0; h01 < 2; ++h01) {
                const int hgl = (ob >> 6) + h01;
                const size_t o = (((size_t)b * H_ + hgl) * L_ + lb + l) * DH + hf * 32;
                const int cbase = h01 * 72 + hf * 32;
                uint4 v0 = *reinterpret_cast<const uint4*>(&sT[l][cbase]);
                uint4 v1 = *reinterpret_cast<const uint4*>(&sT[l][cbase + 8]);
                uint4 v2 = *reinterpret_cast<const uint4*>(&sT[l][cbase + 16]);
                uint4 v3 = *reinterpret_cast<const uint4*>(&sT[l][cbase + 24]);
                *reinterpret_cast<uint4*>(&dst[o])      = v0;
                *reinterpret_cast<uint4*>(&dst[o + 8])  = v1;
                *reinterpret_cast<uint4*>(&dst[o + 16]) = v2;
                *reinterpret_cast<uint4*>(&dst[o + 24]) = v3;
            }
        }
    }
}

// ---------------------------------------------------------------------------
// Attention v12: v8 structure (LDS-staged K/V, 1 barrier/tile — the proven
// best) + SWAPPED QK^T.  mfma(K,Q) puts per-lane P values at one q-row
// (col=lc) and four CONSECUTIVE j (row=quad*4+r): pairs (r,r+1) are
// j-adjacent, so the P->bf16 transpose becomes 8 v_cvt_pk_bf16_f32 + 4
// ds_write_b64 per tile (was: 16 scalar f2bf ≈64 VALU + 16 ds_write_b16).
// The LDS image of P is byte-identical to v8's Pl[q_row][j], so pf
// read-back, rowsum-MFMA, PV, rv, acc layouts and epilogue are UNCHANGED.
// Only: QK operand order, bias index math (diff = j-(rowW+lc), rs row=lc),
// and the exp/store block differ.  cvt_pk is RNE == f2bf: numerics equal.
// ---------------------------------------------------------------------------
__global__ __launch_bounds__(512, 4) void attn_kernel12(
    const unsigned short* __restrict__ Qb,   // bf16 (B,H,L,Dh), pre-scaled
    const unsigned short* __restrict__ Kb,   // bf16 (B,H,L,Dh)
    const unsigned short* __restrict__ Vc,   // bf16 (B,C,L)
    const float* __restrict__ erel_k, const float* __restrict__ erel_v,
    unsigned short* __restrict__ AOh)        // f16 (B,L,C)
{
    __shared__ __align__(16) unsigned short kst[2][64][68];  // [buf][j][d]
    __shared__ __align__(16) unsigned short vst[2][64][68];  // [buf][d][j]
    __shared__ __align__(16) unsigned short Pl[8][16][68];   // per-wave P[q_row][j]
    __shared__ float rs[128][9];
    __shared__ float rv[128][9];

    const int t  = threadIdx.x;
    const int bh = blockIdx.x;          // 0..63  (id%8==h -> XCD L2 locality)
    const int rt = blockIdx.y;          // 0..7
    const int b = bh >> 3, h = bh & 7;
    const int w = t >> 6, lane = t & 63, quad = lane >> 4, lc = lane & 15;
    const int row0 = rt * 128;
    const int rowW = row0 + w * 16;     // wave's 16 rows

    const size_t qkBase = (size_t)bh * L_ * DH;
    const size_t vBase  = ((size_t)b * C_ + h * DH) * L_;

    for (int i = lane; i < 16 * 9; i += 64) rv[w * 16 + i / 9][i % 9] = 0.f;

    // Q A-fragments (16 rows), reused across all 16 key tiles
    short8 af[2];
#pragma unroll
    for (int kk = 0; kk < 2; ++kk)
        af[kk] = *reinterpret_cast<const short8*>(
            &Qb[qkBase + (size_t)(rowW + lc) * DH + kk * 32 + quad * 8]);

    // rel-k scores via MFMA: B[n=dr][k=d] = erk[dr][d]
    {
        floatx4 rsa = (floatx4)0.f;
        const int drow = (lc < 9) ? lc : 8;
#pragma unroll
        for (int kk = 0; kk < 2; ++kk) {
            short8 bfr;
#pragma unroll
            for (int i = 0; i < 8; ++i)
                bfr[i] = (short)f2bf(erel_k[drow * 64 + kk * 32 + quad * 8 + i]);
            rsa = __builtin_amdgcn_mfma_f32_16x16x32_bf16(af[kk], bfr, rsa, 0, 0, 0);
        }
        if (lc < 9) {
#pragma unroll
            for (int r = 0; r < 4; ++r)
                rs[w * 16 + quad * 4 + r][lc] = rsa[r];
        }
    }

    // stage tile 0 (512 thr: one uint4 per thread per array covers 64x64)
    const int jr = t >> 3, jc = (t & 7) * 8;
    *reinterpret_cast<uint4*>(&kst[0][jr][jc]) =
        *reinterpret_cast<const uint4*>(&Kb[qkBase + (size_t)jr * DH + jc]);
    *reinterpret_cast<uint4*>(&vst[0][jr][jc]) =
        *reinterpret_cast<const uint4*>(&Vc[vBase + (size_t)jr * L_ + jc]);
    __syncthreads();

    short8 ones;
#pragma unroll
    for (int j = 0; j < 8; ++j) ones[j] = (short)0x3F80;

    floatx4 acc_o[4], acc_l = (floatx4)0.f;
#pragma unroll
    for (int nt = 0; nt < 4; ++nt) acc_o[nt] = (floatx4)0.f;

    for (int jt = 0; jt < L_ / 64; ++jt) {
        const int j0  = jt * 64;
        const int cur = jt & 1;

        // register prefetch of next tile
        uint4 pk, pv;
        if (jt < L_ / 64 - 1) {
            const int j0n = j0 + 64;
            pk = *reinterpret_cast<const uint4*>(
                &Kb[qkBase + (size_t)(j0n + jr) * DH + jc]);
            pv = *reinterpret_cast<const uint4*>(
                &Vc[vBase + (size_t)jr * L_ + j0n + jc]);
        }

        // S^T = K Q^T (swapped): lane holds S[q=rowW+lc][j=j0+nt*16+quad*4+r]
        floatx4 sacc[4];
#pragma unroll
        for (int nt = 0; nt < 4; ++nt) sacc[nt] = (floatx4)0.f;
#pragma unroll
        for (int nt = 0; nt < 4; ++nt)
#pragma unroll
            for (int kk = 0; kk < 2; ++kk) {
                const short8 kf = *reinterpret_cast<const short8*>(
                    &kst[cur][nt * 16 + lc][kk * 32 + quad * 8]);
                sacc[nt] = __builtin_amdgcn_mfma_f32_16x16x32_bf16(kf, af[kk], sacc[nt], 0, 0, 0);
            }

        // windowed rel-k bias (near-diagonal tiles only); rs row = this
        // lane's q-row (lc), col = diff+WIN
        const bool nearD = (j0 <= rowW + 15 + WIN) && (j0 + 63 >= rowW - WIN);
        if (nearD) {
#pragma unroll
            for (int nt = 0; nt < 4; ++nt) {
#pragma unroll
                for (int r = 0; r < 4; ++r) {
                    const int diff = (j0 + nt * 16 + quad * 4 + r) - (rowW + lc);
                    if (diff >= -WIN && diff <= WIN)
                        sacc[nt][r] += rs[w * 16 + lc][diff + WIN];
                }
            }
        }

        // exp (no max subtraction; scores bounded ~|6|); pack j-adjacent
        // pairs with v_cvt_pk_bf16_f32 (RNE), store as ds_write_b64.
        // LDS image: Pl[w][q_row=lc][j] — identical layout to v8.
#pragma unroll
        for (int nt = 0; nt < 4; ++nt) {
            const float e0 = __expf(sacc[nt][0]);
            const float e1 = __expf(sacc[nt][1]);
            const float e2 = __expf(sacc[nt][2]);
            const float e3 = __expf(sacc[nt][3]);
            unsigned int u01, u23;
            asm("v_cvt_pk_bf16_f32 %0, %1, %2" : "=v"(u01) : "v"(e0), "v"(e1));
            asm("v_cvt_pk_bf16_f32 %0, %1, %2" : "=v"(u23) : "v"(e2), "v"(e3));
            uint2 pr; pr.x = u01; pr.y = u23;
            *reinterpret_cast<uint2*>(&Pl[w][lc][nt * 16 + quad * 4]) = pr;
        }

        // rel-v prob accumulation (gated; wave-private rows, in-order DS)
        if (nearD) {
            for (int idx = lane; idx < 16 * 9; idx += 64) {
                const int r16 = idx / 9, dr = idx % 9;
                const int jg = rowW + r16 + dr - WIN;
                if (jg >= j0 && jg < j0 + 64 && jg >= 0 && jg < L_)
                    rv[w * 16 + r16][dr] += bf2f(Pl[w][r16][jg - j0]);
            }
        }

        // P back as A-fragments (unchanged: Pl layout == v8)
        short8 pf[2];
#pragma unroll
        for (int kk = 0; kk < 2; ++kk)
            pf[kk] = *reinterpret_cast<const short8*>(&Pl[w][lc][kk * 32 + quad * 8]);

        // row sums via MFMA
#pragma unroll
        for (int kk = 0; kk < 2; ++kk)
            acc_l = __builtin_amdgcn_mfma_f32_16x16x32_bf16(pf[kk], ones, acc_l, 0, 0, 0);

        // O += P V  (V B-frags from LDS)
#pragma unroll
        for (int nt = 0; nt < 4; ++nt)
#pragma unroll
            for (int kk = 0; kk < 2; ++kk) {
                const short8 vf = *reinterpret_cast<const short8*>(
                    &vst[cur][nt * 16 + lc][kk * 32 + quad * 8]);
                acc_o[nt] = __builtin_amdgcn_mfma_f32_16x16x32_bf16(pf[kk], vf, acc_o[nt], 0, 0, 0);
            }

        // commit prefetched tile, then sync
        if (jt < L_ / 64 - 1) {
            *reinterpret_cast<uint4*>(&kst[1 - cur][jr][jc]) = pk;
            *reinterpret_cast<uint4*>(&vst[1 - cur][jr][jc]) = pv;
        }
        __syncthreads();
    }

    // epilogue: rel-v term, normalize, transpose via Pl, full-line f16 stores
#pragma unroll
    for (int nt = 0; nt < 4; ++nt) {
        const int d = nt * 16 + lc;
        float ev[9];
#pragma unroll
        for (int dr = 0; dr < 9; ++dr) ev[dr] = erel_v[dr * 64 + d];
#pragma unroll
        for (int r = 0; r < 4; ++r) {
            const int rloc = w * 16 + quad * 4 + r;
            float v = acc_o[nt][r];
#pragma unroll
            for (int dr = 0; dr < 9; ++dr) v += rv[rloc][dr] * ev[dr];
            Pl[w][quad * 4 + r][nt * 16 + lc] = f2h(v / acc_l[r]);
        }
    }
    {
        const int row = lane >> 2, ds8 = (lane & 3) * 16;
        const uint4 q0 = *reinterpret_cast<const uint4*>(&Pl[w][row][ds8]);
        const uint4 q1 = *reinterpret_cast<const uint4*>(&Pl[w][row][ds8 + 8]);
        const size_t o = ((size_t)b * L_ + rowW + row) * C_ + h * 64 + ds8;
        *reinterpret_cast<uint4*>(&AOh[o])     = q0;
        *reinterpret_cast<uint4*>(&AOh[o + 8]) = q1;
    }
}

// ---------------------------------------------------------------------------
// Output projection v2: 1-term f16, double-buffered LDS + register prefetch,
// one barrier per K-step.  M-tile 128 x N-tile 64 x K=512.
// ---------------------------------------------------------------------------
__global__ __launch_bounds__(256) void out_gemm_kernel(
    const unsigned short* __restrict__ Wh,
    const float* __restrict__ bo,
    const unsigned short* __restrict__ Ah,
    float* __restrict__ Y)
{
    __shared__ __align__(16) unsigned short Asb[2][128][40];
    __shared__ __align__(16) unsigned short Bsb[2][64][40];

    const int b  = blockIdx.z;
    const int ob = blockIdx.y * 128;
    const int lb = blockIdx.x * 64;
    const int t  = threadIdx.x;
    const int w = t >> 6, lane = t & 63, quad = lane >> 4, lc = lane & 15;
    const int wm = w >> 1, wn = w & 1;

    floatx4 acc[4][2];
#pragma unroll
    for (int i = 0; i < 4; ++i)
#pragma unroll
        for (int j = 0; j < 2; ++j) acc[i][j] = (floatx4)0.f;

    const int c8 = (t & 3) * 8, r0 = t >> 2;

    // stage step 0
#pragma unroll
    for (int p = 0; p < 2; ++p)
        *reinterpret_cast<uint4*>(&Asb[0][r0 + 64 * p][c8]) =
            *reinterpret_cast<const uint4*>(&Wh[(size_t)(ob + r0 + 64 * p) * C_ + c8]);
    *reinterpret_cast<uint4*>(&Bsb[0][r0][c8]) =
        *reinterpret_cast<const uint4*>(&Ah[((size_t)b * L_ + lb + r0) * C_ + c8]);
    __syncthreads();

    for (int s = 0; s < 16; ++s) {
        const int cur = s & 1;

        uint4 pa[2], pb;
        if (s < 15) {
            const int c0n = (s + 1) * 32;
#pragma unroll
            for (int p = 0; p < 2; ++p)
                pa[p] = *reinterpret_cast<const uint4*>(
                    &Wh[(size_t)(ob + r0 + 64 * p) * C_ + c0n + c8]);
            pb = *reinterpret_cast<const uint4*>(
                &Ah[((size_t)b * L_ + lb + r0) * C_ + c0n + c8]);
        }

        short8 ah[4], bhf[2];
#pragma unroll
        for (int mt = 0; mt < 4; ++mt)
            ah[mt] = *reinterpret_cast<const short8*>(
                &Asb[cur][wm * 64 + mt * 16 + lc][quad * 8]);
#pragma unroll
        for (int nt = 0; nt < 2; ++nt)
            bhf[nt] = *reinterpret_cast<const short8*>(
                &Bsb[cur][wn * 32 + nt * 16 + lc][quad * 8]);
#pragma unroll
        for (int mt = 0; mt < 4; ++mt)
#pragma unroll
            for (int nt = 0; nt < 2; ++nt)
                acc[mt][nt] = __builtin_amdgcn_mfma_f32_16x16x32_f16(
                    ah[mt], bhf[nt], acc[mt][nt], 0, 0, 0);

        if (s < 15) {
#pragma unroll
            for (int p = 0; p < 2; ++p)
                *reinterpret_cast<uint4*>(&Asb[1 - cur][r0 + 64 * p][c8]) = pa[p];
            *reinterpret_cast<uint4*>(&Bsb[1 - cur][r0][c8]) = pb;
        }
        __syncthreads();
    }

#pragma unroll
    for (int mt = 0; mt < 4; ++mt) {
#pragma unroll
        for (int r = 0; r < 4; ++r) {
            const int o = ob + wm * 64 + mt * 16 + quad * 4 + r;
            const float bi = bo[o];
#pragma unroll
            for (int nt = 0; nt < 2; ++nt) {
                const int l = lb + wn * 32 + nt * 16 + lc;
                Y[((size_t)b * C_ + o) * L_ + l] = acc[mt][nt][r] + bi;
            }
        }
    }
}

// ---------------------------------------------------------------------------
extern "C" void kernel_launch(void* const* d_in, const int* in_sizes, int n_in,
                              void* d_out, int out_size, void* d_ws, size_t ws_size,
                              hipStream_t stream)
{
    const float* x   = (const float*)d_in[0];
    const float* Wq  = (const float*)d_in[1];
    const float* bq  = (const float*)d_in[2];
    const float* Wk  = (const float*)d_in[3];
    const float* bk  = (const float*)d_in[4];
    const float* Wv  = (const float*)d_in[5];
    const float* bv  = (const float*)d_in[6];
    const float* Wo  = (const float*)d_in[7];
    const float* bo  = (const float*)d_in[8];
    const float* erk = (const float*)d_in[9];
    const float* erv = (const float*)d_in[10];

    char* ws = (char*)d_ws;
    const size_t MB = 1024u * 1024u;
    unsigned short* xT      = (unsigned short*)(ws);             // 8 MB
    unsigned short* Qb      = (unsigned short*)(ws + 8 * MB);    // 8 MB (B,H,L,Dh)
    unsigned short* Kb      = (unsigned short*)(ws + 16 * MB);   // 8 MB (B,H,L,Dh)
    unsigned short* Vc      = (unsigned short*)(ws + 24 * MB);   // 8 MB (B,C,L)
    unsigned short* AOh     = (unsigned short*)(ws + 32 * MB);   // 8 MB f16 (B,L,C)
    unsigned short* Wqkv_hi = (unsigned short*)(ws + 40 * MB);   // 1.5 MB
    unsigned short* Wo_h    = (unsigned short*)(ws + 42 * MB);   // 0.5 MB f16
    float*          bqkv    = (float*)(ws + 43 * MB);            // 6 KB

    prep_kernel<<<256, 256, 0, stream>>>(Wq, Wk, Wv, Wo, bq, bk, bv,
                                         Wqkv_hi, Wo_h, bqkv);
    transpose_kernel<<<dim3(L_ / 32, C_ / 32, B_), 256, 0, stream>>>(x, xT);
    qkv_gemm_kernel<<<dim3(L_ / 128, 12, B_), 256, 0, stream>>>(
        Wqkv_hi, bqkv, xT, Qb, Kb, Vc);
    attn_kernel12<<<dim3(64, 8), 512, 0, stream>>>(
        Qb, Kb, Vc, erk, erv, AOh);
    out_gemm_kernel<<<dim3(L_ / 64, C_ / 128, B_), 256, 0, stream>>>(
        Wo_h, bo, AOh, (float*)d_out);
}

// Round 5
// 166.966 us; speedup vs baseline: 1.5013x; 1.0166x over previous
//
#include <hip/hip_runtime.h>
#include <math.h>

#define B_  8
#define H_  8
#define C_  512
#define L_  1024
#define DH  64
#define WIN 4

typedef __attribute__((ext_vector_type(8))) short short8;
typedef __attribute__((ext_vector_type(4))) float floatx4;

__device__ __forceinline__ unsigned short f2bf(float f) {
    unsigned int u = __float_as_uint(f);
    u = u + 0x7FFFu + ((u >> 16) & 1u);     // RNE
    return (unsigned short)(u >> 16);
}
__device__ __forceinline__ float bf2f(unsigned short h) {
    return __uint_as_float(((unsigned int)h) << 16);
}
__device__ __forceinline__ unsigned short f2h(float f) {
    _Float16 h = (_Float16)f;
    return *reinterpret_cast<unsigned short*>(&h);
}

// async global->LDS, 16B per lane; dest = wave-uniform base + lane*16
__device__ __forceinline__ void gload_lds16(const void* g, void* l) {
    __builtin_amdgcn_global_load_lds(
        (const __attribute__((address_space(1))) void*)g,
        (__attribute__((address_space(3))) void*)l, 16, 0, 0);
}

// ---------------------------------------------------------------------------
// prep: Wq/Wk/Wv -> bf16 (packed 3x512x512), Wo -> f16, pack biases.
// ---------------------------------------------------------------------------
__global__ __launch_bounds__(256) void prep_kernel(
    const float* __restrict__ Wq, const float* __restrict__ Wk,
    const float* __restrict__ Wv, const float* __restrict__ Wo,
    const float* __restrict__ bq, const float* __restrict__ bk,
    const float* __restrict__ bv,
    unsigned short* __restrict__ Wqkv_hi,
    unsigned short* __restrict__ Wo_h,
    float* __restrict__ bqkv)
{
    const int i = blockIdx.x * 256 + threadIdx.x;   // 65536 float4 slots
    float4 v; ushort4 h;

    v = ((const float4*)Wq)[i];
    h.x = f2bf(v.x); h.y = f2bf(v.y); h.z = f2bf(v.z); h.w = f2bf(v.w);
    ((ushort4*)Wqkv_hi)[i] = h;

    v = ((const float4*)Wk)[i];
    h.x = f2bf(v.x); h.y = f2bf(v.y); h.z = f2bf(v.z); h.w = f2bf(v.w);
    ((ushort4*)Wqkv_hi)[65536 + i] = h;

    v = ((const float4*)Wv)[i];
    h.x = f2bf(v.x); h.y = f2bf(v.y); h.z = f2bf(v.z); h.w = f2bf(v.w);
    ((ushort4*)Wqkv_hi)[131072 + i] = h;

    v = ((const float4*)Wo)[i];
    h.x = f2h(v.x); h.y = f2h(v.y); h.z = f2h(v.z); h.w = f2h(v.w);
    ((ushort4*)Wo_h)[i] = h;

    if (i < 512)       bqkv[i] = bq[i];
    else if (i < 1024) bqkv[i] = bk[i - 512];
    else if (i < 1536) bqkv[i] = bv[i - 1024];
}

// ---------------------------------------------------------------------------
// x (B,C,L) fp32 -> xT bf16 (B,L,C).  32x32 LDS transpose.
// ---------------------------------------------------------------------------
__global__ __launch_bounds__(256) void transpose_kernel(
    const float* __restrict__ x, unsigned short* __restrict__ xT)
{
    __shared__ float tile[32][33];
    const int b  = blockIdx.z;
    const int cb = blockIdx.y * 32;
    const int lb = blockIdx.x * 32;
    const int t  = threadIdx.x;
    {
        const int l = t & 31, c0 = t >> 5;
#pragma unroll
        for (int p = 0; p < 4; ++p) {
            const int c = c0 + 8 * p;
            tile[c][l] = x[((size_t)b * C_ + cb + c) * L_ + lb + l];
        }
    }
    __syncthreads();
    {
        const int c = t & 31, l0 = t >> 5;
#pragma unroll
        for (int p = 0; p < 4; ++p) {
            const int l = l0 + 8 * p;
            xT[((size_t)b * L_ + lb + l) * C_ + cb + c] = f2bf(tile[c][l]);
        }
    }
}

// ---------------------------------------------------------------------------
// Fused QKV GEMM v3: global_load_lds staging (m97 structure; m151 measured
// +35% vs reg-staging at 128^2).  LDS tiles LINEAR [128][32] (gload_lds
// dest must be wave-uniform-base + lane*16: row w*32+p*16+(lane>>2),
// col (lane&3)*8 linearizes to base+lane*16).  8-way ds_read bank
// conflicts accepted per m97/m98 evidence (874 TF despite 1.7e7 conflicts).
// One barrier per K-step; loads for s+1 issued before MFMAs of s; the
// vmcnt(0)+barrier drain makes buf^1 ready for s+1.  Epilogue sT[128][144]
// (36864 B) aliases SM (18432 shorts = max of both uses).
// ---------------------------------------------------------------------------
__global__ __launch_bounds__(256) void qkv_gemm_kernel(
    const unsigned short* __restrict__ Wh, const float* __restrict__ bqkv,
    const unsigned short* __restrict__ xT,
    unsigned short* __restrict__ Qb, unsigned short* __restrict__ Kb,
    unsigned short* __restrict__ Vc)
{
    // [mat A=0/B=1][buf][128][32] tiles, 4096 shorts each; 16384 used,
    // 18432 allocated so the epilogue sT[128][144] fits in the same block.
    __shared__ __align__(16) unsigned short SM[18432];

    const int b   = blockIdx.z;
    const int oB  = blockIdx.y * 128;
    const int mat = oB >> 9;                // 0=Q,1=K,2=V
    const int ob  = oB & 511;
    const int lb  = blockIdx.x * 128;
    const int t  = threadIdx.x;
    const int w = t >> 6, lane = t & 63, quad = lane >> 4, lc = lane & 15;
    const int wm = w >> 1, wn = w & 1;

    const unsigned short* Wm = Wh + (size_t)mat * C_ * C_;

    floatx4 acc[4][4];
#pragma unroll
    for (int i = 0; i < 4; ++i)
#pragma unroll
        for (int j = 0; j < 4; ++j) acc[i][j] = (floatx4)0.f;

    const int srow = w * 32 + (lane >> 2);      // staging row (+16 for p=1)
    const int sc8  = (lane & 3) * 8;            // staging col (elements)

    // STAGE(buf, s): issue 4 gload_lds16 per thread (2 rows A, 2 rows B)
#define QKV_STAGE(BUF, S) {                                                  \
    const int c0_ = (S) * 32;                                                \
    _Pragma("unroll")                                                        \
    for (int p_ = 0; p_ < 2; ++p_) {                                         \
        gload_lds16(&Wm[(size_t)(ob + srow + 16 * p_) * C_ + c0_ + sc8],     \
                    &SM[(0 * 2 + (BUF)) * 4096 + (w * 32 + p_ * 16) * 32]);  \
        gload_lds16(&xT[((size_t)b * L_ + lb + srow + 16 * p_) * C_ + c0_ + sc8], \
                    &SM[(1 * 2 + (BUF)) * 4096 + (w * 32 + p_ * 16) * 32]);  \
    }                                                                        \
}

    QKV_STAGE(0, 0)
    __syncthreads();

    for (int s = 0; s < 16; ++s) {
        const int cur = s & 1;
        if (s < 15) QKV_STAGE(1 - cur, s + 1)

        const unsigned short (*At)[32] =
            reinterpret_cast<const unsigned short (*)[32]>(&SM[(0 * 2 + cur) * 4096]);
        const unsigned short (*Bt)[32] =
            reinterpret_cast<const unsigned short (*)[32]>(&SM[(1 * 2 + cur) * 4096]);

        short8 a[4], bb[4];
#pragma unroll
        for (int mt = 0; mt < 4; ++mt)
            a[mt] = *reinterpret_cast<const short8*>(&At[wm * 64 + mt * 16 + lc][quad * 8]);
#pragma unroll
        for (int nt = 0; nt < 4; ++nt)
            bb[nt] = *reinterpret_cast<const short8*>(&Bt[wn * 64 + nt * 16 + lc][quad * 8]);
#pragma unroll
        for (int mt = 0; mt < 4; ++mt)
#pragma unroll
            for (int nt = 0; nt < 4; ++nt)
                acc[mt][nt] = __builtin_amdgcn_mfma_f32_16x16x32_bf16(
                    a[mt], bb[nt], acc[mt][nt], 0, 0, 0);

        __syncthreads();   // drains vmcnt(0): buf^1 complete; all reads retired
    }

    if (mat == 2) {
        // V: direct coalesced (B,C,L)
#pragma unroll
        for (int mt = 0; mt < 4; ++mt) {
#pragma unroll
            for (int r = 0; r < 4; ++r) {
                const int o  = ob + wm * 64 + mt * 16 + quad * 4 + r;
                const float bi = bqkv[1024 + o];
#pragma unroll
                for (int nt = 0; nt < 4; ++nt) {
                    const int l = lb + wn * 64 + nt * 16 + lc;
                    Vc[((size_t)b * C_ + o) * L_ + l] = f2bf(acc[mt][nt][r] + bi);
                }
            }
        }
    } else {
        // Q/K: single-pass dual-head LDS transpose (sT aliases SM; the final
        // K-loop barrier has retired all reads of SM)
        const float scale = (mat == 0) ? 0.125f : 1.0f;
        unsigned short* dst = (mat == 0) ? Qb : Kb;
        unsigned short (*sT)[144] =
            reinterpret_cast<unsigned short (*)[144]>(&SM[0]);

        // wave (wm, wn): head wm, l-range wn*64..+63 — all waves concurrent
#pragma unroll
        for (int mt = 0; mt < 4; ++mt) {
#pragma unroll
            for (int r = 0; r < 4; ++r) {
                const int o  = ob + wm * 64 + mt * 16 + quad * 4 + r;
                const float bi = bqkv[mat * 512 + o];
                const int d  = mt * 16 + quad * 4 + r;
#pragma unroll
                for (int nt = 0; nt < 4; ++nt) {
                    const int l = wn * 64 + nt * 16 + lc;
                    sT[l][wm * 72 + d] = f2bf((acc[mt][nt][r] + bi) * scale);
                }
            }
        }
        __syncthreads();
        {
            const int l = t >> 1, hf = t & 1;
#pragma unroll
            for (int h01 = 0; h01 < 2; ++h01) {
                const int hgl = (ob >> 6) + h01;
                const size_t o = (((size_t)b * H_ + hgl) * L_ + lb + l) * DH + hf * 32;
                const int cbase = h01 * 72 + hf * 32;
                uint4 v0 = *reinterpret_cast<const uint4*>(&sT[l][cbase]);
                uint4 v1 = *reinterpret_cast<const uint4*>(&sT[l][cbase + 8]);
                uint4 v2 = *reinterpret_cast<const uint4*>(&sT[l][cbase + 16]);
                uint4 v3 = *reinterpret_cast<const uint4*>(&sT[l][cbase + 24]);
                *reinterpret_cast<uint4*>(&dst[o])      = v0;
                *reinterpret_cast<uint4*>(&dst[o + 8])  = v1;
                *reinterpret_cast<uint4*>(&dst[o + 16]) = v2;
                *reinterpret_cast<uint4*>(&dst[o + 24]) = v3;
            }
        }
    }
}

// ---------------------------------------------------------------------------
// Attention v12 (unchanged from R3 — measured 45.2 us): v8 structure +
// swapped QK^T, cvt_pk bf16 pack, ds_write_b64 P-store.
// ---------------------------------------------------------------------------
__global__ __launch_bounds__(512, 4) void attn_kernel12(
    const unsigned short* __restrict__ Qb,   // bf16 (B,H,L,Dh), pre-scaled
    const unsigned short* __restrict__ Kb,   // bf16 (B,H,L,Dh)
    const unsigned short* __restrict__ Vc,   // bf16 (B,C,L)
    const float* __restrict__ erel_k, const float* __restrict__ erel_v,
    unsigned short* __restrict__ AOh)        // f16 (B,L,C)
{
    __shared__ __align__(16) unsigned short kst[2][64][68];  // [buf][j][d]
    __shared__ __align__(16) unsigned short vst[2][64][68];  // [buf][d][j]
    __shared__ __align__(16) unsigned short Pl[8][16][68];   // per-wave P[q_row][j]
    __shared__ float rs[128][9];
    __shared__ float rv[128][9];

    const int t  = threadIdx.x;
    const int bh = blockIdx.x;          // 0..63  (id%8==h -> XCD L2 locality)
    const int rt = blockIdx.y;          // 0..7
    const int b = bh >> 3, h = bh & 7;
    const int w = t >> 6, lane = t & 63, quad = lane >> 4, lc = lane & 15;
    const int row0 = rt * 128;
    const int rowW = row0 + w * 16;     // wave's 16 rows

    const size_t qkBase = (size_t)bh * L_ * DH;
    const size_t vBase  = ((size_t)b * C_ + h * DH) * L_;

    for (int i = lane; i < 16 * 9; i += 64) rv[w * 16 + i / 9][i % 9] = 0.f;

    // Q A-fragments (16 rows), reused across all 16 key tiles
    short8 af[2];
#pragma unroll
    for (int kk = 0; kk < 2; ++kk)
        af[kk] = *reinterpret_cast<const short8*>(
            &Qb[qkBase + (size_t)(rowW + lc) * DH + kk * 32 + quad * 8]);

    // rel-k scores via MFMA: B[n=dr][k=d] = erk[dr][d]
    {
        floatx4 rsa = (floatx4)0.f;
        const int drow = (lc < 9) ? lc : 8;
#pragma unroll
        for (int kk = 0; kk < 2; ++kk) {
            short8 bfr;
#pragma unroll
            for (int i = 0; i < 8; ++i)
                bfr[i] = (short)f2bf(erel_k[drow * 64 + kk * 32 + quad * 8 + i]);
            rsa = __builtin_amdgcn_mfma_f32_16x16x32_bf16(af[kk], bfr, rsa, 0, 0, 0);
        }
        if (lc < 9) {
#pragma unroll
            for (int r = 0; r < 4; ++r)
                rs[w * 16 + quad * 4 + r][lc] = rsa[r];
        }
    }

    // stage tile 0 (512 thr: one uint4 per thread per array covers 64x64)
    const int jr = t >> 3, jc = (t & 7) * 8;
    *reinterpret_cast<uint4*>(&kst[0][jr][jc]) =
        *reinterpret_cast<const uint4*>(&Kb[qkBase + (size_t)jr * DH + jc]);
    *reinterpret_cast<uint4*>(&vst[0][jr][jc]) =
        *reinterpret_cast<const uint4*>(&Vc[vBase + (size_t)jr * L_ + jc]);
    __syncthreads();

    short8 ones;
#pragma unroll
    for (int j = 0; j < 8; ++j) ones[j] = (short)0x3F80;

    floatx4 acc_o[4], acc_l = (floatx4)0.f;
#pragma unroll
    for (int nt = 0; nt < 4; ++nt) acc_o[nt] = (floatx4)0.f;

    for (int jt = 0; jt < L_ / 64; ++jt) {
        const int j0  = jt * 64;
        const int cur = jt & 1;

        // register prefetch of next tile
        uint4 pk, pv;
        if (jt < L_ / 64 - 1) {
            const int j0n = j0 + 64;
            pk = *reinterpret_cast<const uint4*>(
                &Kb[qkBase + (size_t)(j0n + jr) * DH + jc]);
            pv = *reinterpret_cast<const uint4*>(
                &Vc[vBase + (size_t)jr * L_ + j0n + jc]);
        }

        // S^T = K Q^T (swapped): lane holds S[q=rowW+lc][j=j0+nt*16+quad*4+r]
        floatx4 sacc[4];
#pragma unroll
        for (int nt = 0; nt < 4; ++nt) sacc[nt] = (floatx4)0.f;
#pragma unroll
        for (int nt = 0; nt < 4; ++nt)
#pragma unroll
            for (int kk = 0; kk < 2; ++kk) {
                const short8 kf = *reinterpret_cast<const short8*>(
                    &kst[cur][nt * 16 + lc][kk * 32 + quad * 8]);
                sacc[nt] = __builtin_amdgcn_mfma_f32_16x16x32_bf16(kf, af[kk], sacc[nt], 0, 0, 0);
            }

        // windowed rel-k bias (near-diagonal tiles only); rs row = this
        // lane's q-row (lc), col = diff+WIN
        const bool nearD = (j0 <= rowW + 15 + WIN) && (j0 + 63 >= rowW - WIN);
        if (nearD) {
#pragma unroll
            for (int nt = 0; nt < 4; ++nt) {
#pragma unroll
                for (int r = 0; r < 4; ++r) {
                    const int diff = (j0 + nt * 16 + quad * 4 + r) - (rowW + lc);
                    if (diff >= -WIN && diff <= WIN)
                        sacc[nt][r] += rs[w * 16 + lc][diff + WIN];
                }
            }
        }

        // exp (no max subtraction; scores bounded ~|6|); pack j-adjacent
        // pairs with v_cvt_pk_bf16_f32 (RNE), store as ds_write_b64.
        // LDS image: Pl[w][q_row=lc][j] — identical layout to v8.
#pragma unroll
        for (int nt = 0; nt < 4; ++nt) {
            const float e0 = __expf(sacc[nt][0]);
            const float e1 = __expf(sacc[nt][1]);
            const float e2 = __expf(sacc[nt][2]);
            const float e3 = __expf(sacc[nt][3]);
            unsigned int u01, u23;
            asm("v_cvt_pk_bf16_f32 %0, %1, %2" : "=v"(u01) : "v"(e0), "v"(e1));
            asm("v_cvt_pk_bf16_f32 %0, %1, %2" : "=v"(u23) : "v"(e2), "v"(e3));
            uint2 pr; pr.x = u01; pr.y = u23;
            *reinterpret_cast<uint2*>(&Pl[w][lc][nt * 16 + quad * 4]) = pr;
        }

        // rel-v prob accumulation (gated; wave-private rows, in-order DS)
        if (nearD) {
            for (int idx = lane; idx < 16 * 9; idx += 64) {
                const int r16 = idx / 9, dr = idx % 9;
                const int jg = rowW + r16 + dr - WIN;
                if (jg >= j0 && jg < j0 + 64 && jg >= 0 && jg < L_)
                    rv[w * 16 + r16][dr] += bf2f(Pl[w][r16][jg - j0]);
            }
        }

        // P back as A-fragments (unchanged: Pl layout == v8)
        short8 pf[2];
#pragma unroll
        for (int kk = 0; kk < 2; ++kk)
            pf[kk] = *reinterpret_cast<const short8*>(&Pl[w][lc][kk * 32 + quad * 8]);

        // row sums via MFMA
#pragma unroll
        for (int kk = 0; kk < 2; ++kk)
            acc_l = __builtin_amdgcn_mfma_f32_16x16x32_bf16(pf[kk], ones, acc_l, 0, 0, 0);

        // O += P V  (V B-frags from LDS)
#pragma unroll
        for (int nt = 0; nt < 4; ++nt)
#pragma unroll
            for (int kk = 0; kk < 2; ++kk) {
                const short8 vf = *reinterpret_cast<const short8*>(
                    &vst[cur][nt * 16 + lc][kk * 32 + quad * 8]);
                acc_o[nt] = __builtin_amdgcn_mfma_f32_16x16x32_bf16(pf[kk], vf, acc_o[nt], 0, 0, 0);
            }

        // commit prefetched tile, then sync
        if (jt < L_ / 64 - 1) {
            *reinterpret_cast<uint4*>(&kst[1 - cur][jr][jc]) = pk;
            *reinterpret_cast<uint4*>(&vst[1 - cur][jr][jc]) = pv;
        }
        __syncthreads();
    }

    // epilogue: rel-v term, normalize, transpose via Pl, full-line f16 stores
#pragma unroll
    for (int nt = 0; nt < 4; ++nt) {
        const int d = nt * 16 + lc;
        float ev[9];
#pragma unroll
        for (int dr = 0; dr < 9; ++dr) ev[dr] = erel_v[dr * 64 + d];
#pragma unroll
        for (int r = 0; r < 4; ++r) {
            const int rloc = w * 16 + quad * 4 + r;
            float v = acc_o[nt][r];
#pragma unroll
            for (int dr = 0; dr < 9; ++dr) v += rv[rloc][dr] * ev[dr];
            Pl[w][quad * 4 + r][nt * 16 + lc] = f2h(v / acc_l[r]);
        }
    }
    {
        const int row = lane >> 2, ds8 = (lane & 3) * 16;
        const uint4 q0 = *reinterpret_cast<const uint4*>(&Pl[w][row][ds8]);
        const uint4 q1 = *reinterpret_cast<const uint4*>(&Pl[w][row][ds8 + 8]);
        const size_t o = ((size_t)b * L_ + rowW + row) * C_ + h * 64 + ds8;
        *reinterpret_cast<uint4*>(&AOh[o])     = q0;
        *reinterpret_cast<uint4*>(&AOh[o + 8]) = q1;
    }
}

// ---------------------------------------------------------------------------
// Output projection v3: global_load_lds staging, linear LDS [*][32],
// one barrier per K-step (same m97 schedule as qkv v3).
// M-tile 128 x N-tile 64 x K=512, f16 MFMA.
// ---------------------------------------------------------------------------
__global__ __launch_bounds__(256) void out_gemm_kernel(
    const unsigned short* __restrict__ Wh,
    const float* __restrict__ bo,
    const unsigned short* __restrict__ Ah,
    float* __restrict__ Y)
{
    __shared__ __align__(16) unsigned short Asb[2][128][32];   // 16 KB
    __shared__ __align__(16) unsigned short Bsb[2][64][32];    // 8 KB

    const int b  = blockIdx.z;
    const int ob = blockIdx.y * 128;
    const int lb = blockIdx.x * 64;
    const int t  = threadIdx.x;
    const int w = t >> 6, lane = t & 63, quad = lane >> 4, lc = lane & 15;
    const int wm = w >> 1, wn = w & 1;

    floatx4 acc[4][2];
#pragma unroll
    for (int i = 0; i < 4; ++i)
#pragma unroll
        for (int j = 0; j < 2; ++j) acc[i][j] = (floatx4)0.f;

    const int srow = (lane >> 2);            // within-16-row offset
    const int sc8  = (lane & 3) * 8;

#define OG_STAGE(BUF, S) {                                                   \
    const int c0_ = (S) * 32;                                                \
    _Pragma("unroll")                                                        \
    for (int p_ = 0; p_ < 2; ++p_)                                           \
        gload_lds16(&Wh[(size_t)(ob + w * 32 + p_ * 16 + srow) * C_ + c0_ + sc8], \
                    &Asb[BUF][w * 32 + p_ * 16][0]);                         \
    gload_lds16(&Ah[((size_t)b * L_ + lb + w * 16 + srow) * C_ + c0_ + sc8], \
                &Bsb[BUF][w * 16][0]);                                       \
}

    OG_STAGE(0, 0)
    __syncthreads();

    for (int s = 0; s < 16; ++s) {
        const int cur = s & 1;
        if (s < 15) OG_STAGE(1 - cur, s + 1)

        short8 ah[4], bhf[2];
#pragma unroll
        for (int mt = 0; mt < 4; ++mt)
            ah[mt] = *reinterpret_cast<const short8*>(
                &Asb[cur][wm * 64 + mt * 16 + lc][quad * 8]);
#pragma unroll
        for (int nt = 0; nt < 2; ++nt)
            bhf[nt] = *reinterpret_cast<const short8*>(
                &Bsb[cur][wn * 32 + nt * 16 + lc][quad * 8]);
#pragma unroll
        for (int mt = 0; mt < 4; ++mt)
#pragma unroll
            for (int nt = 0; nt < 2; ++nt)
                acc[mt][nt] = __builtin_amdgcn_mfma_f32_16x16x32_f16(
                    ah[mt], bhf[nt], acc[mt][nt], 0, 0, 0);

        __syncthreads();
    }

#pragma unroll
    for (int mt = 0; mt < 4; ++mt) {
#pragma unroll
        for (int r = 0; r < 4; ++r) {
            const int o = ob + wm * 64 + mt * 16 + quad * 4 + r;
            const float bi = bo[o];
#pragma unroll
            for (int nt = 0; nt < 2; ++nt) {
                const int l = lb + wn * 32 + nt * 16 + lc;
                Y[((size_t)b * C_ + o) * L_ + l] = acc[mt][nt][r] + bi;
            }
        }
    }
}

// ---------------------------------------------------------------------------
extern "C" void kernel_launch(void* const* d_in, const int* in_sizes, int n_in,
                              void* d_out, int out_size, void* d_ws, size_t ws_size,
                              hipStream_t stream)
{
    const float* x   = (const float*)d_in[0];
    const float* Wq  = (const float*)d_in[1];
    const float* bq  = (const float*)d_in[2];
    const float* Wk  = (const float*)d_in[3];
    const float* bk  = (const float*)d_in[4];
    const float* Wv  = (const float*)d_in[5];
    const float* bv  = (const float*)d_in[6];
    const float* Wo  = (const float*)d_in[7];
    const float* bo  = (const float*)d_in[8];
    const float* erk = (const float*)d_in[9];
    const float* erv = (const float*)d_in[10];

    char* ws = (char*)d_ws;
    const size_t MB = 1024u * 1024u;
    unsigned short* xT      = (unsigned short*)(ws);             // 8 MB
    unsigned short* Qb      = (unsigned short*)(ws + 8 * MB);    // 8 MB (B,H,L,Dh)
    unsigned short* Kb      = (unsigned short*)(ws + 16 * MB);   // 8 MB (B,H,L,Dh)
    unsigned short* Vc      = (unsigned short*)(ws + 24 * MB);   // 8 MB (B,C,L)
    unsigned short* AOh     = (unsigned short*)(ws + 32 * MB);   // 8 MB f16 (B,L,C)
    unsigned short* Wqkv_hi = (unsigned short*)(ws + 40 * MB);   // 1.5 MB
    unsigned short* Wo_h    = (unsigned short*)(ws + 42 * MB);   // 0.5 MB f16
    float*          bqkv    = (float*)(ws + 43 * MB);            // 6 KB

    prep_kernel<<<256, 256, 0, stream>>>(Wq, Wk, Wv, Wo, bq, bk, bv,
                                         Wqkv_hi, Wo_h, bqkv);
    transpose_kernel<<<dim3(L_ / 32, C_ / 32, B_), 256, 0, stream>>>(x, xT);
    qkv_gemm_kernel<<<dim3(L_ / 128, 12, B_), 256, 0, stream>>>(
        Wqkv_hi, bqkv, xT, Qb, Kb, Vc);
    attn_kernel12<<<dim3(64, 8), 512, 0, stream>>>(
        Qb, Kb, Vc, erk, erv, AOh);
    out_gemm_kernel<<<dim3(L_ / 64, C_ / 128, B_), 256, 0, stream>>>(
        Wo_h, bo, AOh, (float*)d_out);
}

// Round 7
// 165.396 us; speedup vs baseline: 1.5156x; 1.0095x over previous
//
#include <hip/hip_runtime.h>
#include <math.h>

#define B_  8
#define H_  8
#define C_  512
#define L_  1024
#define DH  64
#define WIN 4

typedef __attribute__((ext_vector_type(8))) short short8;
typedef __attribute__((ext_vector_type(4))) float floatx4;

__device__ __forceinline__ unsigned short f2bf(float f) {
    unsigned int u = __float_as_uint(f);
    u = u + 0x7FFFu + ((u >> 16) & 1u);     // RNE
    return (unsigned short)(u >> 16);
}
__device__ __forceinline__ float bf2f(unsigned short h) {
    return __uint_as_float(((unsigned int)h) << 16);
}
__device__ __forceinline__ unsigned short f2h(float f) {
    _Float16 h = (_Float16)f;
    return *reinterpret_cast<unsigned short*>(&h);
}

// async global->LDS, 16B per lane; dest = wave-uniform base + lane*16
__device__ __forceinline__ void gload_lds16(const void* g, void* l) {
    __builtin_amdgcn_global_load_lds(
        (const __attribute__((address_space(1))) void*)g,
        (__attribute__((address_space(3))) void*)l, 16, 0, 0);
}

// ---------------------------------------------------------------------------
// prep: Wq/Wk/Wv -> bf16 (packed 3x512x512), Wo -> f16, pack biases.
// ---------------------------------------------------------------------------
__global__ __launch_bounds__(256) void prep_kernel(
    const float* __restrict__ Wq, const float* __restrict__ Wk,
    const float* __restrict__ Wv, const float* __restrict__ Wo,
    const float* __restrict__ bq, const float* __restrict__ bk,
    const float* __restrict__ bv,
    unsigned short* __restrict__ Wqkv_hi,
    unsigned short* __restrict__ Wo_h,
    float* __restrict__ bqkv)
{
    const int i = blockIdx.x * 256 + threadIdx.x;   // 65536 float4 slots
    float4 v; ushort4 h;

    v = ((const float4*)Wq)[i];
    h.x = f2bf(v.x); h.y = f2bf(v.y); h.z = f2bf(v.z); h.w = f2bf(v.w);
    ((ushort4*)Wqkv_hi)[i] = h;

    v = ((const float4*)Wk)[i];
    h.x = f2bf(v.x); h.y = f2bf(v.y); h.z = f2bf(v.z); h.w = f2bf(v.w);
    ((ushort4*)Wqkv_hi)[65536 + i] = h;

    v = ((const float4*)Wv)[i];
    h.x = f2bf(v.x); h.y = f2bf(v.y); h.z = f2bf(v.z); h.w = f2bf(v.w);
    ((ushort4*)Wqkv_hi)[131072 + i] = h;

    v = ((const float4*)Wo)[i];
    h.x = f2h(v.x); h.y = f2h(v.y); h.z = f2h(v.z); h.w = f2h(v.w);
    ((ushort4*)Wo_h)[i] = h;

    if (i < 512)       bqkv[i] = bq[i];
    else if (i < 1024) bqkv[i] = bk[i - 512];
    else if (i < 1536) bqkv[i] = bv[i - 1024];
}

// ---------------------------------------------------------------------------
// x (B,C,L) fp32 -> xT bf16 (B,L,C).  32x32 LDS transpose.
// ---------------------------------------------------------------------------
__global__ __launch_bounds__(256) void transpose_kernel(
    const float* __restrict__ x, unsigned short* __restrict__ xT)
{
    __shared__ float tile[32][33];
    const int b  = blockIdx.z;
    const int cb = blockIdx.y * 32;
    const int lb = blockIdx.x * 32;
    const int t  = threadIdx.x;
    {
        const int l = t & 31, c0 = t >> 5;
#pragma unroll
        for (int p = 0; p < 4; ++p) {
            const int c = c0 + 8 * p;
            tile[c][l] = x[((size_t)b * C_ + cb + c) * L_ + lb + l];
        }
    }
    __syncthreads();
    {
        const int c = t & 31, l0 = t >> 5;
#pragma unroll
        for (int p = 0; p < 4; ++p) {
            const int l = l0 + 8 * p;
            xT[((size_t)b * L_ + lb + l) * C_ + cb + c] = f2bf(tile[c][l]);
        }
    }
}

// ---------------------------------------------------------------------------
// Fused QKV GEMM v3: global_load_lds staging (m97 structure), linear LDS
// [128][32] tiles, one barrier per K-step.  Epilogue sT[128][144] aliases SM.
// ---------------------------------------------------------------------------
__global__ __launch_bounds__(256) void qkv_gemm_kernel(
    const unsigned short* __restrict__ Wh, const float* __restrict__ bqkv,
    const unsigned short* __restrict__ xT,
    unsigned short* __restrict__ Qb, unsigned short* __restrict__ Kb,
    unsigned short* __restrict__ Vc)
{
    __shared__ __align__(16) unsigned short SM[18432];

    const int b   = blockIdx.z;
    const int oB  = blockIdx.y * 128;
    const int mat = oB >> 9;                // 0=Q,1=K,2=V
    const int ob  = oB & 511;
    const int lb  = blockIdx.x * 128;
    const int t  = threadIdx.x;
    const int w = t >> 6, lane = t & 63, quad = lane >> 4, lc = lane & 15;
    const int wm = w >> 1, wn = w & 1;

    const unsigned short* Wm = Wh + (size_t)mat * C_ * C_;

    floatx4 acc[4][4];
#pragma unroll
    for (int i = 0; i < 4; ++i)
#pragma unroll
        for (int j = 0; j < 4; ++j) acc[i][j] = (floatx4)0.f;

    const int srow = w * 32 + (lane >> 2);      // staging row (+16 for p=1)
    const int sc8  = (lane & 3) * 8;            // staging col (elements)

#define QKV_STAGE(BUF, S) {                                                  \
    const int c0_ = (S) * 32;                                                \
    _Pragma("unroll")                                                        \
    for (int p_ = 0; p_ < 2; ++p_) {                                         \
        gload_lds16(&Wm[(size_t)(ob + srow + 16 * p_) * C_ + c0_ + sc8],     \
                    &SM[(0 * 2 + (BUF)) * 4096 + (w * 32 + p_ * 16) * 32]);  \
        gload_lds16(&xT[((size_t)b * L_ + lb + srow + 16 * p_) * C_ + c0_ + sc8], \
                    &SM[(1 * 2 + (BUF)) * 4096 + (w * 32 + p_ * 16) * 32]);  \
    }                                                                        \
}

    QKV_STAGE(0, 0)
    __syncthreads();

    for (int s = 0; s < 16; ++s) {
        const int cur = s & 1;
        if (s < 15) QKV_STAGE(1 - cur, s + 1)

        const unsigned short (*At)[32] =
            reinterpret_cast<const unsigned short (*)[32]>(&SM[(0 * 2 + cur) * 4096]);
        const unsigned short (*Bt)[32] =
            reinterpret_cast<const unsigned short (*)[32]>(&SM[(1 * 2 + cur) * 4096]);

        short8 a[4], bb[4];
#pragma unroll
        for (int mt = 0; mt < 4; ++mt)
            a[mt] = *reinterpret_cast<const short8*>(&At[wm * 64 + mt * 16 + lc][quad * 8]);
#pragma unroll
        for (int nt = 0; nt < 4; ++nt)
            bb[nt] = *reinterpret_cast<const short8*>(&Bt[wn * 64 + nt * 16 + lc][quad * 8]);
#pragma unroll
        for (int mt = 0; mt < 4; ++mt)
#pragma unroll
            for (int nt = 0; nt < 4; ++nt)
                acc[mt][nt] = __builtin_amdgcn_mfma_f32_16x16x32_bf16(
                    a[mt], bb[nt], acc[mt][nt], 0, 0, 0);

        __syncthreads();
    }

    if (mat == 2) {
#pragma unroll
        for (int mt = 0; mt < 4; ++mt) {
#pragma unroll
            for (int r = 0; r < 4; ++r) {
                const int o  = ob + wm * 64 + mt * 16 + quad * 4 + r;
                const float bi = bqkv[1024 + o];
#pragma unroll
                for (int nt = 0; nt < 4; ++nt) {
                    const int l = lb + wn * 64 + nt * 16 + lc;
                    Vc[((size_t)b * C_ + o) * L_ + l] = f2bf(acc[mt][nt][r] + bi);
                }
            }
        }
    } else {
        const float scale = (mat == 0) ? 0.125f : 1.0f;
        unsigned short* dst = (mat == 0) ? Qb : Kb;
        unsigned short (*sT)[144] =
            reinterpret_cast<unsigned short (*)[144]>(&SM[0]);

#pragma unroll
        for (int mt = 0; mt < 4; ++mt) {
#pragma unroll
            for (int r = 0; r < 4; ++r) {
                const int o  = ob + wm * 64 + mt * 16 + quad * 4 + r;
                const float bi = bqkv[mat * 512 + o];
                const int d  = mt * 16 + quad * 4 + r;
#pragma unroll
                for (int nt = 0; nt < 4; ++nt) {
                    const int l = wn * 64 + nt * 16 + lc;
                    sT[l][wm * 72 + d] = f2bf((acc[mt][nt][r] + bi) * scale);
                }
            }
        }
        __syncthreads();
        {
            const int l = t >> 1, hf = t & 1;
#pragma unroll
            for (int h01 = 0; h01 < 2; ++h01) {
                const int hgl = (ob >> 6) + h01;
                const size_t o = (((size_t)b * H_ + hgl) * L_ + lb + l) * DH + hf * 32;
                const int cbase = h01 * 72 + hf * 32;
                uint4 v0 = *reinterpret_cast<const uint4*>(&sT[l][cbase]);
                uint4 v1 = *reinterpret_cast<const uint4*>(&sT[l][cbase + 8]);
                uint4 v2 = *reinterpret_cast<const uint4*>(&sT[l][cbase + 16]);
                uint4 v3 = *reinterpret_cast<const uint4*>(&sT[l][cbase + 24]);
                *reinterpret_cast<uint4*>(&dst[o])      = v0;
                *reinterpret_cast<uint4*>(&dst[o + 8])  = v1;
                *reinterpret_cast<uint4*>(&dst[o + 16]) = v2;
                *reinterpret_cast<uint4*>(&dst[o + 24]) = v3;
            }
        }
    }
}

// ---------------------------------------------------------------------------
// Attention v13a: 2 q-row groups per wave (32 rows), each K/V ds_read feeds
// 2 MFMAs (halves the dominant LDS read traffic vs v12).  v13's failure is
// isolated to the Pl time-share between groups (the only new dataflow; all
// index remaps re-verified against v12): here each group gets its OWN Pl
// buffer Pl[w][g] — no write-after-read reuse at all, correct by
// construction.  LDS 61440 B -> 2 blocks/CU (8 waves/CU): tests LDS-traffic
// reduction vs occupancy.  All per-group math is byte-identical to v12.
// ---------------------------------------------------------------------------
__global__ __launch_bounds__(256, 2) void attn_kernel13a(
    const unsigned short* __restrict__ Qb,   // bf16 (B,H,L,Dh), pre-scaled
    const unsigned short* __restrict__ Kb,   // bf16 (B,H,L,Dh)
    const unsigned short* __restrict__ Vc,   // bf16 (B,C,L)
    const float* __restrict__ erel_k, const float* __restrict__ erel_v,
    unsigned short* __restrict__ AOh)        // f16 (B,L,C)
{
    __shared__ __align__(16) unsigned short kst[2][64][68];   // 17408 B
    __shared__ __align__(16) unsigned short vst[2][64][68];   // 17408 B
    __shared__ __align__(16) unsigned short Pl[4][2][16][68]; // 17408 B
    __shared__ float rs[128][9];                              //  4608 B
    __shared__ float rv[128][9];                              //  4608 B

    const int t  = threadIdx.x;
    const int bh = blockIdx.x;          // 0..63  (id%8==h -> XCD L2 locality)
    const int rt = blockIdx.y;          // 0..7
    const int b = bh >> 3, h = bh & 7;
    const int w = t >> 6, lane = t & 63, quad = lane >> 4, lc = lane & 15;
    const int rowB = rt * 128 + w * 32; // wave's 32 rows; group g: rowB+g*16

    const size_t qkBase = (size_t)bh * L_ * DH;
    const size_t vBase  = ((size_t)b * C_ + h * DH) * L_;

    for (int i = lane; i < 32 * 9; i += 64) rv[w * 32 + i / 9][i % 9] = 0.f;

    // Q A-fragments for both groups
    short8 af0[2], af1[2];
#pragma unroll
    for (int kk = 0; kk < 2; ++kk) {
        af0[kk] = *reinterpret_cast<const short8*>(
            &Qb[qkBase + (size_t)(rowB + lc) * DH + kk * 32 + quad * 8]);
        af1[kk] = *reinterpret_cast<const short8*>(
            &Qb[qkBase + (size_t)(rowB + 16 + lc) * DH + kk * 32 + quad * 8]);
    }

    // rel-k scores via MFMA (bfr built once, shared by both groups)
    {
        floatx4 rsa0 = (floatx4)0.f, rsa1 = (floatx4)0.f;
        const int drow = (lc < 9) ? lc : 8;
#pragma unroll
        for (int kk = 0; kk < 2; ++kk) {
            short8 bfr;
#pragma unroll
            for (int i = 0; i < 8; ++i)
                bfr[i] = (short)f2bf(erel_k[drow * 64 + kk * 32 + quad * 8 + i]);
            rsa0 = __builtin_amdgcn_mfma_f32_16x16x32_bf16(af0[kk], bfr, rsa0, 0, 0, 0);
            rsa1 = __builtin_amdgcn_mfma_f32_16x16x32_bf16(af1[kk], bfr, rsa1, 0, 0, 0);
        }
        if (lc < 9) {
#pragma unroll
            for (int r = 0; r < 4; ++r) {
                rs[w * 32 + quad * 4 + r][lc]      = rsa0[r];
                rs[w * 32 + 16 + quad * 4 + r][lc] = rsa1[r];
            }
        }
    }

    // stage tile 0 (256 thr: 2 uint4 per thread per array covers 64x64)
    const int jr = t >> 2, jcE = (t & 3) * 16;
    *reinterpret_cast<uint4*>(&kst[0][jr][jcE]) =
        *reinterpret_cast<const uint4*>(&Kb[qkBase + (size_t)jr * DH + jcE]);
    *reinterpret_cast<uint4*>(&kst[0][jr][jcE + 8]) =
        *reinterpret_cast<const uint4*>(&Kb[qkBase + (size_t)jr * DH + jcE + 8]);
    *reinterpret_cast<uint4*>(&vst[0][jr][jcE]) =
        *reinterpret_cast<const uint4*>(&Vc[vBase + (size_t)jr * L_ + jcE]);
    *reinterpret_cast<uint4*>(&vst[0][jr][jcE + 8]) =
        *reinterpret_cast<const uint4*>(&Vc[vBase + (size_t)jr * L_ + jcE + 8]);
    __syncthreads();

    short8 ones;
#pragma unroll
    for (int j = 0; j < 8; ++j) ones[j] = (short)0x3F80;

    floatx4 acc_o0[4], acc_o1[4], acc_l0 = (floatx4)0.f, acc_l1 = (floatx4)0.f;
#pragma unroll
    for (int nt = 0; nt < 4; ++nt) { acc_o0[nt] = (floatx4)0.f; acc_o1[nt] = (floatx4)0.f; }

    for (int jt = 0; jt < L_ / 64; ++jt) {
        const int j0  = jt * 64;
        const int cur = jt & 1;

        // register prefetch of next tile (4 uint4)
        uint4 pk0, pk1, pv0, pv1;
        if (jt < L_ / 64 - 1) {
            const int j0n = j0 + 64;
            pk0 = *reinterpret_cast<const uint4*>(
                &Kb[qkBase + (size_t)(j0n + jr) * DH + jcE]);
            pk1 = *reinterpret_cast<const uint4*>(
                &Kb[qkBase + (size_t)(j0n + jr) * DH + jcE + 8]);
            pv0 = *reinterpret_cast<const uint4*>(
                &Vc[vBase + (size_t)jr * L_ + j0n + jcE]);
            pv1 = *reinterpret_cast<const uint4*>(
                &Vc[vBase + (size_t)jr * L_ + j0n + jcE + 8]);
        }

        // S^T = K Q^T for BOTH groups: each kf read feeds 2 MFMAs
        floatx4 s0[4], s1[4];
#pragma unroll
        for (int nt = 0; nt < 4; ++nt) { s0[nt] = (floatx4)0.f; s1[nt] = (floatx4)0.f; }
#pragma unroll
        for (int nt = 0; nt < 4; ++nt)
#pragma unroll
            for (int kk = 0; kk < 2; ++kk) {
                const short8 kf = *reinterpret_cast<const short8*>(
                    &kst[cur][nt * 16 + lc][kk * 32 + quad * 8]);
                s0[nt] = __builtin_amdgcn_mfma_f32_16x16x32_bf16(kf, af0[kk], s0[nt], 0, 0, 0);
                s1[nt] = __builtin_amdgcn_mfma_f32_16x16x32_bf16(kf, af1[kk], s1[nt], 0, 0, 0);
            }

        short8 pf0[2], pf1[2];

        // ---- group 0: bias, exp->Pl[w][0], rv, pf0 ----
        {
            const int rowW = rowB;
            const bool nearD = (j0 <= rowW + 15 + WIN) && (j0 + 63 >= rowW - WIN);
            if (nearD) {
#pragma unroll
                for (int nt = 0; nt < 4; ++nt)
#pragma unroll
                    for (int r = 0; r < 4; ++r) {
                        const int diff = (j0 + nt * 16 + quad * 4 + r) - (rowW + lc);
                        if (diff >= -WIN && diff <= WIN)
                            s0[nt][r] += rs[w * 32 + lc][diff + WIN];
                    }
            }
#pragma unroll
            for (int nt = 0; nt < 4; ++nt) {
                const float e0 = __expf(s0[nt][0]);
                const float e1 = __expf(s0[nt][1]);
                const float e2 = __expf(s0[nt][2]);
                const float e3 = __expf(s0[nt][3]);
                unsigned int u01, u23;
                asm volatile("v_cvt_pk_bf16_f32 %0, %1, %2" : "=v"(u01) : "v"(e0), "v"(e1));
                asm volatile("v_cvt_pk_bf16_f32 %0, %1, %2" : "=v"(u23) : "v"(e2), "v"(e3));
                uint2 pr; pr.x = u01; pr.y = u23;
                *reinterpret_cast<uint2*>(&Pl[w][0][lc][nt * 16 + quad * 4]) = pr;
            }
            if (nearD) {
                for (int idx = lane; idx < 16 * 9; idx += 64) {
                    const int r16 = idx / 9, dr = idx % 9;
                    const int jg = rowW + r16 + dr - WIN;
                    if (jg >= j0 && jg < j0 + 64 && jg >= 0 && jg < L_)
                        rv[w * 32 + r16][dr] += bf2f(Pl[w][0][r16][jg - j0]);
                }
            }
#pragma unroll
            for (int kk = 0; kk < 2; ++kk)
                pf0[kk] = *reinterpret_cast<const short8*>(&Pl[w][0][lc][kk * 32 + quad * 8]);
        }

        // ---- group 1: bias, exp->Pl[w][1] (own buffer), rv, pf1 ----
        {
            const int rowW = rowB + 16;
            const bool nearD = (j0 <= rowW + 15 + WIN) && (j0 + 63 >= rowW - WIN);
            if (nearD) {
#pragma unroll
                for (int nt = 0; nt < 4; ++nt)
#pragma unroll
                    for (int r = 0; r < 4; ++r) {
                        const int diff = (j0 + nt * 16 + quad * 4 + r) - (rowW + lc);
                        if (diff >= -WIN && diff <= WIN)
                            s1[nt][r] += rs[w * 32 + 16 + lc][diff + WIN];
                    }
            }
#pragma unroll
            for (int nt = 0; nt < 4; ++nt) {
                const float e0 = __expf(s1[nt][0]);
                const float e1 = __expf(s1[nt][1]);
                const float e2 = __expf(s1[nt][2]);
                const float e3 = __expf(s1[nt][3]);
                unsigned int u01, u23;
                asm volatile("v_cvt_pk_bf16_f32 %0, %1, %2" : "=v"(u01) : "v"(e0), "v"(e1));
                asm volatile("v_cvt_pk_bf16_f32 %0, %1, %2" : "=v"(u23) : "v"(e2), "v"(e3));
                uint2 pr; pr.x = u01; pr.y = u23;
                *reinterpret_cast<uint2*>(&Pl[w][1][lc][nt * 16 + quad * 4]) = pr;
            }
            if (nearD) {
                for (int idx = lane; idx < 16 * 9; idx += 64) {
                    const int r16 = idx / 9, dr = idx % 9;
                    const int jg = rowW + r16 + dr - WIN;
                    if (jg >= j0 && jg < j0 + 64 && jg >= 0 && jg < L_)
                        rv[w * 32 + 16 + r16][dr] += bf2f(Pl[w][1][r16][jg - j0]);
                }
            }
#pragma unroll
            for (int kk = 0; kk < 2; ++kk)
                pf1[kk] = *reinterpret_cast<const short8*>(&Pl[w][1][lc][kk * 32 + quad * 8]);
        }

        // row sums via MFMA (both groups)
#pragma unroll
        for (int kk = 0; kk < 2; ++kk) {
            acc_l0 = __builtin_amdgcn_mfma_f32_16x16x32_bf16(pf0[kk], ones, acc_l0, 0, 0, 0);
            acc_l1 = __builtin_amdgcn_mfma_f32_16x16x32_bf16(pf1[kk], ones, acc_l1, 0, 0, 0);
        }

        // O += P V: each vf read feeds 2 MFMAs
#pragma unroll
        for (int nt = 0; nt < 4; ++nt)
#pragma unroll
            for (int kk = 0; kk < 2; ++kk) {
                const short8 vf = *reinterpret_cast<const short8*>(
                    &vst[cur][nt * 16 + lc][kk * 32 + quad * 8]);
                acc_o0[nt] = __builtin_amdgcn_mfma_f32_16x16x32_bf16(pf0[kk], vf, acc_o0[nt], 0, 0, 0);
                acc_o1[nt] = __builtin_amdgcn_mfma_f32_16x16x32_bf16(pf1[kk], vf, acc_o1[nt], 0, 0, 0);
            }

        // commit prefetched tile, then sync
        if (jt < L_ / 64 - 1) {
            *reinterpret_cast<uint4*>(&kst[1 - cur][jr][jcE])     = pk0;
            *reinterpret_cast<uint4*>(&kst[1 - cur][jr][jcE + 8]) = pk1;
            *reinterpret_cast<uint4*>(&vst[1 - cur][jr][jcE])     = pv0;
            *reinterpret_cast<uint4*>(&vst[1 - cur][jr][jcE + 8]) = pv1;
        }
        __syncthreads();
    }

    // epilogue group 0: rel-v term, normalize, transpose via Pl[w][0], store
    {
#pragma unroll
        for (int nt = 0; nt < 4; ++nt) {
            const int d = nt * 16 + lc;
            float ev[9];
#pragma unroll
            for (int dr = 0; dr < 9; ++dr) ev[dr] = erel_v[dr * 64 + d];
#pragma unroll
            for (int r = 0; r < 4; ++r) {
                const int rloc = w * 32 + quad * 4 + r;
                float v = acc_o0[nt][r];
#pragma unroll
                for (int dr = 0; dr < 9; ++dr) v += rv[rloc][dr] * ev[dr];
                Pl[w][0][quad * 4 + r][nt * 16 + lc] = f2h(v / acc_l0[r]);
            }
        }
        const int row = lane >> 2, ds8 = (lane & 3) * 16;
        const uint4 q0 = *reinterpret_cast<const uint4*>(&Pl[w][0][row][ds8]);
        const uint4 q1 = *reinterpret_cast<const uint4*>(&Pl[w][0][row][ds8 + 8]);
        const size_t o = ((size_t)b * L_ + rowB + row) * C_ + h * 64 + ds8;
        *reinterpret_cast<uint4*>(&AOh[o])     = q0;
        *reinterpret_cast<uint4*>(&AOh[o + 8]) = q1;
    }
    // epilogue group 1
    {
#pragma unroll
        for (int nt = 0; nt < 4; ++nt) {
            const int d = nt * 16 + lc;
            float ev[9];
#pragma unroll
            for (int dr = 0; dr < 9; ++dr) ev[dr] = erel_v[dr * 64 + d];
#pragma unroll
            for (int r = 0; r < 4; ++r) {
                const int rloc = w * 32 + 16 + quad * 4 + r;
                float v = acc_o1[nt][r];
#pragma unroll
                for (int dr = 0; dr < 9; ++dr) v += rv[rloc][dr] * ev[dr];
                Pl[w][1][quad * 4 + r][nt * 16 + lc] = f2h(v / acc_l1[r]);
            }
        }
        const int row = lane >> 2, ds8 = (lane & 3) * 16;
        const uint4 q0 = *reinterpret_cast<const uint4*>(&Pl[w][1][row][ds8]);
        const uint4 q1 = *reinterpret_cast<const uint4*>(&Pl[w][1][row][ds8 + 8]);
        const size_t o = ((size_t)b * L_ + rowB + 16 + row) * C_ + h * 64 + ds8;
        *reinterpret_cast<uint4*>(&AOh[o])     = q0;
        *reinterpret_cast<uint4*>(&AOh[o + 8]) = q1;
    }
}

// ---------------------------------------------------------------------------
// Output projection v3: global_load_lds staging, linear LDS [*][32],
// one barrier per K-step.  M-tile 128 x N-tile 64 x K=512, f16 MFMA.
// ---------------------------------------------------------------------------
__global__ __launch_bounds__(256) void out_gemm_kernel(
    const unsigned short* __restrict__ Wh,
    const float* __restrict__ bo,
    const unsigned short* __restrict__ Ah,
    float* __restrict__ Y)
{
    __shared__ __align__(16) unsigned short Asb[2][128][32];   // 16 KB
    __shared__ __align__(16) unsigned short Bsb[2][64][32];    // 8 KB

    const int b  = blockIdx.z;
    const int ob = blockIdx.y * 128;
    const int lb = blockIdx.x * 64;
    const int t  = threadIdx.x;
    const int w = t >> 6, lane = t & 63, quad = lane >> 4, lc = lane & 15;
    const int wm = w >> 1, wn = w & 1;

    floatx4 acc[4][2];
#pragma unroll
    for (int i = 0; i < 4; ++i)
#pragma unroll
        for (int j = 0; j < 2; ++j) acc[i][j] = (floatx4)0.f;

    const int srow = (lane >> 2);            // within-16-row offset
    const int sc8  = (lane & 3) * 8;

#define OG_STAGE(BUF, S) {                                                   \
    const int c0_ = (S) * 32;                                                \
    _Pragma("unroll")                                                        \
    for (int p_ = 0; p_ < 2; ++p_)                                           \
        gload_lds16(&Wh[(size_t)(ob + w * 32 + p_ * 16 + srow) * C_ + c0_ + sc8], \
                    &Asb[BUF][w * 32 + p_ * 16][0]);                         \
    gload_lds16(&Ah[((size_t)b * L_ + lb + w * 16 + srow) * C_ + c0_ + sc8], \
                &Bsb[BUF][w * 16][0]);                                       \
}

    OG_STAGE(0, 0)
    __syncthreads();

    for (int s = 0; s < 16; ++s) {
        const int cur = s & 1;
        if (s < 15) OG_STAGE(1 - cur, s + 1)

        short8 ah[4], bhf[2];
#pragma unroll
        for (int mt = 0; mt < 4; ++mt)
            ah[mt] = *reinterpret_cast<const short8*>(
                &Asb[cur][wm * 64 + mt * 16 + lc][quad * 8]);
#pragma unroll
        for (int nt = 0; nt < 2; ++nt)
            bhf[nt] = *reinterpret_cast<const short8*>(
                &Bsb[cur][wn * 32 + nt * 16 + lc][quad * 8]);
#pragma unroll
        for (int mt = 0; mt < 4; ++mt)
#pragma unroll
            for (int nt = 0; nt < 2; ++nt)
                acc[mt][nt] = __builtin_amdgcn_mfma_f32_16x16x32_f16(
                    ah[mt], bhf[nt], acc[mt][nt], 0, 0, 0);

        __syncthreads();
    }

#pragma unroll
    for (int mt = 0; mt < 4; ++mt) {
#pragma unroll
        for (int r = 0; r < 4; ++r) {
            const int o = ob + wm * 64 + mt * 16 + quad * 4 + r;
            const float bi = bo[o];
#pragma unroll
            for (int nt = 0; nt < 2; ++nt) {
                const int l = lb + wn * 32 + nt * 16 + lc;
                Y[((size_t)b * C_ + o) * L_ + l] = acc[mt][nt][r] + bi;
            }
        }
    }
}

// ---------------------------------------------------------------------------
extern "C" void kernel_launch(void* const* d_in, const int* in_sizes, int n_in,
                              void* d_out, int out_size, void* d_ws, size_t ws_size,
                              hipStream_t stream)
{
    const float* x   = (const float*)d_in[0];
    const float* Wq  = (const float*)d_in[1];
    const float* bq  = (const float*)d_in[2];
    const float* Wk  = (const float*)d_in[3];
    const float* bk  = (const float*)d_in[4];
    const float* Wv  = (const float*)d_in[5];
    const float* bv  = (const float*)d_in[6];
    const float* Wo  = (const float*)d_in[7];
    const float* bo  = (const float*)d_in[8];
    const float* erk = (const float*)d_in[9];
    const float* erv = (const float*)d_in[10];

    char* ws = (char*)d_ws;
    const size_t MB = 1024u * 1024u;
    unsigned short* xT      = (unsigned short*)(ws);             // 8 MB
    unsigned short* Qb      = (unsigned short*)(ws + 8 * MB);    // 8 MB (B,H,L,Dh)
    unsigned short* Kb      = (unsigned short*)(ws + 16 * MB);   // 8 MB (B,H,L,Dh)
    unsigned short* Vc      = (unsigned short*)(ws + 24 * MB);   // 8 MB (B,C,L)
    unsigned short* AOh     = (unsigned short*)(ws + 32 * MB);   // 8 MB f16 (B,L,C)
    unsigned short* Wqkv_hi = (unsigned short*)(ws + 40 * MB);   // 1.5 MB
    unsigned short* Wo_h    = (unsigned short*)(ws + 42 * MB);   // 0.5 MB f16
    float*          bqkv    = (float*)(ws + 43 * MB);            // 6 KB

    prep_kernel<<<256, 256, 0, stream>>>(Wq, Wk, Wv, Wo, bq, bk, bv,
                                         Wqkv_hi, Wo_h, bqkv);
    transpose_kernel<<<dim3(L_ / 32, C_ / 32, B_), 256, 0, stream>>>(x, xT);
    qkv_gemm_kernel<<<dim3(L_ / 128, 12, B_), 256, 0, stream>>>(
        Wqkv_hi, bqkv, xT, Qb, Kb, Vc);
    attn_kernel13a<<<dim3(64, 8), 256, 0, stream>>>(
        Qb, Kb, Vc, erk, erv, AOh);
    out_gemm_kernel<<<dim3(L_ / 64, C_ / 128, B_), 256, 0, stream>>>(
        Wo_h, bo, AOh, (float*)d_out);
}